// Round 2
// baseline (11316.883 us; speedup 1.0000x reference)
//
#include <hip/hip_runtime.h>
#include <hip/hip_bf16.h>
#include <math.h>

#define DEV __device__ __forceinline__
typedef unsigned int u32;
typedef unsigned short u16;

constexpr int NNODES = 16384;
constexpr int NEDGE  = 262144;
constexpr int NEL    = NEDGE + NNODES;
constexpr int FIN    = 256;
constexpr int C1     = 384;
constexpr int DM     = 192;
constexpr int BZ     = 128;
constexpr int NPG_   = 128;
constexpr int LL     = 4;
constexpr int PP     = 32;
constexpr int SM     = 33;
constexpr int DFF_   = 512;

// packed-weight layout (uint2 units) per layer
constexpr int PL2     = 104448;
constexpr int OFF_QKV = 0;        // 576x192 -> 48*576
constexpr int OFF_SAO = 27648;    // 192x192 -> 48*192
constexpr int OFF_CAQ = 36864;
constexpr int OFF_CAO = 46080;
constexpr int OFF_FF1 = 55296;    // 512x192 -> 48*512
constexpr int OFF_FF2 = 79872;    // 192x512 -> 128*192
constexpr int OFF_H1  = 4*PL2;            // 417792
constexpr int OFF_H2  = OFF_H1 + 9216;    // 427008 ; +12288 -> 439296 total u2

// ---- workspace layout (float units) ----
constexpr size_t O_XP1 = 0;                       // 6.29M ; later overlapped by bf16 CA-KV (12.58M floats)
constexpr size_t O_H   = 6291456;
constexpr size_t O_XP2 = 12582912;
constexpr size_t O_MEM = 15728640;
constexpr size_t O_VSA = 18874368;                // SA V cache, uint units: BZ*LL*33*96 = 1,622,016
constexpr size_t O_WP  = 20496384;                // packed weights: 439296 uint2 = 878592 floats
constexpr size_t O_PE  = 21374976;
constexpr size_t O_AL1S= O_PE + 6336;
constexpr size_t O_AL1D= O_AL1S + 65536;
constexpr size_t O_AL2S= O_AL1D + 65536;
constexpr size_t O_AL2D= O_AL2S + 16384;
constexpr size_t O_CNT = O_AL2D + 16384;
constexpr size_t O_BASE= O_CNT + 16384;
constexpr size_t O_FILL= O_BASE + 16384;
constexpr size_t O_CSRC= O_FILL + 16384;

DEV float gelu_f(float v) { return 0.5f*v*(1.0f + erff(v*0.7071067811865475f)); }
DEV float bflo(u32 w) { return __uint_as_float(w << 16); }
DEV float bfhi(u32 w) { return __uint_as_float(w & 0xffff0000u); }
DEV float bfu(u16 u)  { return __uint_as_float(((u32)u) << 16); }
DEV u32 pk2(float a, float b) {
  __hip_bfloat16 ha = __float2bfloat16(a), hb = __float2bfloat16(b);
  u32 ua = *reinterpret_cast<u16*>(&ha), ub = *reinterpret_cast<u16*>(&hb);
  return ua | (ub << 16);
}
DEV void fma4(float& a, uint2 w, const float* xv) {
  a = fmaf(bflo(w.x), xv[0], a);
  a = fmaf(bfhi(w.x), xv[1], a);
  a = fmaf(bflo(w.y), xv[2], a);
  a = fmaf(bfhi(w.y), xv[3], a);
}

// ---------------- misc ----------------
__global__ void zero_kernel(float* adj, int* cnt, int* fill) {
  int i = blockIdx.x*256 + threadIdx.x;
  if (i < BZ*SM*SM) adj[i] = 0.f;
  if (i < NNODES) { cnt[i] = 0; fill[i] = 0; }
}

__global__ void pe_kernel(float* pe) {
  int idx = blockIdx.x*256 + threadIdx.x;
  if (idx >= SM*DM) return;
  int p = idx / DM, d = idx % DM;
  int i2 = d >> 1;
  float div = __expf((float)(2*i2) * (-9.210340371976184f / (float)DM));
  float a = (float)p * div;
  pe[idx] = (d & 1) ? cosf(a) : sinf(a);
}

// pack W[N][K] fp32 -> P[kq*N+o] = 4 bf16 of W[o][4kq..4kq+3]
__global__ void pack_kernel(const float* __restrict__ W, uint2* __restrict__ P, int N, int K) {
  int idx = blockIdx.x*256 + threadIdx.x;
  if (idx >= N*(K>>2)) return;
  int o = idx % N, kq = idx / N;
  const float* r = W + (size_t)o*K + 4*kq;
  uint2 u; u.x = pk2(r[0], r[1]); u.y = pk2(r[2], r[3]);
  P[idx] = u;
}

// ---------------- generic fp32 GEMM: C[M,N] = A[M,K] @ W[N,K]^T (+bias) ----------------
template<bool BIAS, bool BF16OUT>
__global__ __launch_bounds__(256) void gemm_nt(const float* __restrict__ A,
    const float* __restrict__ W, const float* __restrict__ bias,
    float* __restrict__ Cf, __hip_bfloat16* __restrict__ Cb, int M, int N, int K)
{
  __shared__ float As[16][68];
  __shared__ float Ws[16][68];
  const int bm = blockIdx.y*64, bn = blockIdx.x*64;
  const int t = threadIdx.x, tx = t & 15, ty = t >> 4;
  float acc[4][4] = {};
  for (int k0 = 0; k0 < K; k0 += 16) {
    #pragma unroll
    for (int i = 0; i < 4; ++i) {
      int idx = t + i*256, kk = idx & 15, m = idx >> 4;
      As[kk][m] = A[(size_t)(bm+m)*K + k0+kk];
      Ws[kk][m] = W[(size_t)(bn+m)*K + k0+kk];
    }
    __syncthreads();
    #pragma unroll
    for (int kk = 0; kk < 16; ++kk) {
      const float4 a4 = *(const float4*)&As[kk][ty*4];
      const float4 b4 = *(const float4*)&Ws[kk][tx*4];
      const float av[4] = {a4.x,a4.y,a4.z,a4.w};
      const float bv[4] = {b4.x,b4.y,b4.z,b4.w};
      #pragma unroll
      for (int i = 0; i < 4; ++i)
        #pragma unroll
        for (int j = 0; j < 4; ++j)
          acc[i][j] = fmaf(av[i], bv[j], acc[i][j]);
    }
    __syncthreads();
  }
  #pragma unroll
  for (int i = 0; i < 4; ++i) {
    const int m = bm + ty*4 + i;
    #pragma unroll
    for (int j = 0; j < 4; ++j) {
      const int n = bn + tx*4 + j;
      float v = acc[i][j];
      if (BIAS) v += bias[n];
      if (BF16OUT) Cb[(size_t)m*N + n] = __float2bfloat16(v);
      else         Cf[(size_t)m*N + n] = v;
    }
  }
}

// ---------------- GAT helpers ----------------
template<int HEADS, int CH>
__global__ void al_kernel(const float* __restrict__ xp, const float* __restrict__ asrc,
                          const float* __restrict__ adst, float* als, float* ald) {
  int idx = blockIdx.x*256 + threadIdx.x;
  if (idx >= NNODES*HEADS) return;
  int n = idx / HEADS, h = idx % HEADS;
  const float* row = xp + (size_t)n*(HEADS*CH) + h*CH;
  float s = 0, d = 0;
  for (int c = 0; c < CH; ++c) { float v = row[c]; s = fmaf(v, asrc[h*CH+c], s); d = fmaf(v, adst[h*CH+c], d); }
  als[idx] = s; ald[idx] = d;
}

__global__ void count_kernel(const int* __restrict__ dst, int* cnt) {
  int e = blockIdx.x*256 + threadIdx.x;
  if (e < NEDGE) atomicAdd(&cnt[dst[e]], 1);
}

__global__ __launch_bounds__(1024) void scan_kernel(const int* __restrict__ cnt, int* base) {
  __shared__ int tot[1024];
  int t = threadIdx.x;
  int local[16]; int s = 0;
  #pragma unroll
  for (int i = 0; i < 16; ++i) { int v = cnt[t*16+i] + 1; local[i] = s; s += v; }
  tot[t] = s; __syncthreads();
  if (t == 0) { int r = 0; for (int i = 0; i < 1024; ++i) { int v = tot[i]; tot[i] = r; r += v; } }
  __syncthreads();
  int off = tot[t];
  #pragma unroll
  for (int i = 0; i < 16; ++i) base[t*16+i] = off + local[i];
}

__global__ void scatter_kernel(const int* __restrict__ src, const int* __restrict__ dst,
                               const int* __restrict__ base, int* fill, int* csrc) {
  int e = blockIdx.x*256 + threadIdx.x;
  if (e < NEDGE) {
    int d = dst[e];
    int p = atomicAdd(&fill[d], 1);
    csrc[base[d] + p] = src[e];
  } else if (e < NEL) {
    int n = e - NEDGE;
    int p = atomicAdd(&fill[n], 1);
    csrc[base[n] + p] = n;
  }
}

template<int HEADS, int CH, bool ELU>
__global__ __launch_bounds__(128) void agg_kernel(const float* __restrict__ xp,
    const float* __restrict__ als, const float* __restrict__ ald,
    const int* __restrict__ cnt, const int* __restrict__ base, const int* __restrict__ csrc,
    const float* __restrict__ bias, float* __restrict__ out)
{
  constexpr int CO = HEADS*CH;
  constexpr int MAXD = 128;
  int n = blockIdx.x, t = threadIdx.x;
  int deg = cnt[n] + 1, st = base[n];
  if (deg > MAXD) deg = MAXD;
  __shared__ int   srcs[MAXD];
  __shared__ float ex[MAXD][HEADS];
  __shared__ float den[HEADS];
  for (int j = t; j < deg; j += 128) srcs[j] = csrc[st + j];
  __syncthreads();
  for (int idx = t; idx < deg*HEADS; idx += 128) {
    int j = idx / HEADS, h = idx % HEADS;
    float e = als[srcs[j]*HEADS + h] + ald[n*HEADS + h];
    ex[j][h] = (e > 0.f) ? e : 0.2f*e;
  }
  __syncthreads();
  if (t < HEADS) {
    float m = -1e30f;
    for (int j = 0; j < deg; ++j) m = fmaxf(m, ex[j][t]);
    float s = 0;
    for (int j = 0; j < deg; ++j) { float v = __expf(ex[j][t]-m); ex[j][t] = v; s += v; }
    den[t] = 1.0f/(s + 1e-16f);
  }
  __syncthreads();
  for (int c = t; c < CO; c += 128) {
    int h = c / CH;
    float acc = 0;
    for (int j = 0; j < deg; ++j) acc = fmaf(ex[j][h], xp[(size_t)srcs[j]*CO + c], acc);
    float v = acc*den[h] + bias[c];
    if (ELU) v = (v > 0.f) ? v : (__expf(v) - 1.0f);
    out[(size_t)n*CO + c] = v;
  }
}

// ---------------- decode ----------------
DEV void ln512(const float* yv, float* xo, int t, const float* g, const float* be, float* red) {
  float v = (t < DM) ? yv[t] : 0.f;
  float s = v, q = v*v;
  #pragma unroll
  for (int o = 32; o; o >>= 1) { s += __shfl_down(s, o, 64); q += __shfl_down(q, o, 64); }
  if ((t & 63) == 0) { red[t>>6] = s; red[8 + (t>>6)] = q; }
  __syncthreads();
  float S = 0, Q = 0;
  #pragma unroll
  for (int w = 0; w < 8; ++w) { S += red[w]; Q += red[8+w]; }
  float mu = S*(1.f/DM), var = Q*(1.f/DM) - mu*mu;
  float rstd = rsqrtf(var + 1e-5f);
  if (t < DM) xo[t] = (yv[t]-mu)*rstd*g[t] + be[t];
  __syncthreads();
}

// split-K2 GEMV, N=192, K=192, packed bf16 weights -> partials in ps[2][192]
DEV void skgemv(const uint2* __restrict__ P, const float* __restrict__ bias,
                const float* __restrict__ xv, float (*ps)[DM], int t) {
  if (t >= 384) return;
  int ks = (t >= 192), o = t - 192*ks;
  const uint2* col = P + o;
  float a = ks ? 0.f : bias[o];
  #pragma unroll
  for (int kq2 = 0; kq2 < 24; ++kq2) {
    int kq = ks*24 + kq2;
    fma4(a, col[(size_t)kq*192], xv + 4*kq);
  }
  ps[ks][o] = a;
}

__global__ __launch_bounds__(512, 2) void decode_kernel(
    const float* __restrict__ mem, const u16* __restrict__ kvb,
    const uint2* __restrict__ wp, const float* __restrict__ pe,
    u32* __restrict__ vsa, const int* __restrict__ tgt_idx,
    const float* __restrict__ saqkvb, const float* __restrict__ saoutb,
    const float* __restrict__ caqkvb, const float* __restrict__ caoutb,
    const float* __restrict__ ff1b, const float* __restrict__ ff2b,
    const float* __restrict__ lng, const float* __restrict__ lnb,
    const float* __restrict__ h1b, const float* __restrict__ h2b,
    float* __restrict__ feats, float* __restrict__ adj)
{
  const int b = blockIdx.x, t = threadIdx.x;
  const int wv = t >> 6, lane = t & 63;
  __shared__ u32   ksa[4*33*97];       // SA K cache, bf16x2, odd dword stride (conflict-free)
  __shared__ float lasts[SM][193];
  __shared__ float x[DM], y[DM], qkv[3*DM], attno[DM], hid[DFF_];
  __shared__ float prob[8][64];
  __shared__ float cprob[8][128];
  __shared__ float ps[2][DM];
  __shared__ float painv[8], cainv[8], red[16];
  const float scl = 0.2041241452319315f; // 1/sqrt(24)
  const float* tgt0 = mem + ((size_t)b*NPG_ + tgt_idx[b])*DM;

  for (int i = 0; i < PP; ++i) {
    if (t < DM) x[t] = ((i == 0) ? tgt0[t] : lasts[i-1][t]) + pe[i*DM + t];
    __syncthreads();
    for (int l = 0; l < LL; ++l) {
      const uint2* WL = wp + (size_t)l*PL2;
      // --- SA qkv: N=576 K=192 ---
      for (int o = t; o < 576; o += 512) {
        const uint2* col = WL + OFF_QKV + o;
        float a = saqkvb[l*576 + o];
        #pragma unroll 16
        for (int kq = 0; kq < 48; ++kq) fma4(a, col[(size_t)kq*576], x + 4*kq);
        qkv[o] = a;
      }
      __syncthreads();
      if (t < 96) vsa[(((size_t)b*LL + l)*SM + i)*96 + t] = pk2(qkv[384+2*t], qkv[385+2*t]);
      else if (t < 192) { int d2 = t-96; ksa[l*3201 + i*97 + d2] = pk2(qkv[192+2*d2], qkv[193+2*d2]); }
      __syncthreads();
      // --- SA QK^T + softmax (wave wv = head) ---
      {
        float s = -1e30f;
        if (lane <= i) {
          const u32* kr = ksa + l*3201 + lane*97 + wv*12;
          float a = 0.f;
          #pragma unroll
          for (int c = 0; c < 12; ++c) {
            u32 w = kr[c];
            a = fmaf(bflo(w), qkv[wv*24 + 2*c],   a);
            a = fmaf(bfhi(w), qkv[wv*24 + 2*c+1], a);
          }
          s = a * scl;
        }
        float m = s;
        #pragma unroll
        for (int o2 = 32; o2; o2 >>= 1) m = fmaxf(m, __shfl_xor(m, o2, 64));
        float e = (lane <= i) ? __expf(s - m) : 0.f;
        float sm = e;
        #pragma unroll
        for (int o2 = 32; o2; o2 >>= 1) sm += __shfl_xor(sm, o2, 64);
        prob[wv][lane] = e;
        if (lane == 0) painv[wv] = 1.0f / sm;
      }
      __syncthreads();
      // --- SA PV ---
      if (t < DM) {
        int hh = t / 24;
        const u16* vb = (const u16*)vsa + (((size_t)b*LL + l)*SM)*192 + t;
        float a = 0.f;
        for (int j = 0; j <= i; ++j) a = fmaf(prob[hh][j], bfu(vb[(size_t)j*192]), a);
        attno[t] = a * painv[hh];
      }
      __syncthreads();
      // --- SA out + residual + LN ---
      skgemv(WL + OFF_SAO, saoutb + l*DM, attno, ps, t);
      __syncthreads();
      if (t < DM) y[t] = x[t] + ps[0][t] + ps[1][t];
      __syncthreads();
      ln512(y, x, t, lng + (l*3+0)*DM, lnb + (l*3+0)*DM, red);
      // --- CA q ---
      skgemv(WL + OFF_CAQ, caqkvb + l*3*DM, x, ps, t);
      __syncthreads();
      if (t < DM) qkv[t] = ps[0][t] + ps[1][t];
      __syncthreads();
      // --- CA QK^T: thread j owns key-row j, computes all 8 head scores ---
      if (t < NPG_) {
        const uint2* kr = (const uint2*)kvb + ((size_t)l*NNODES + (size_t)b*NPG_ + t)*96;
        float sacc[8] = {};
        #pragma unroll
        for (int c = 0; c < 48; ++c) {
          uint2 w = kr[c];
          sacc[c/6] = fmaf(bflo(w.x), qkv[4*c],   sacc[c/6]);
          sacc[c/6] = fmaf(bfhi(w.x), qkv[4*c+1], sacc[c/6]);
          sacc[c/6] = fmaf(bflo(w.y), qkv[4*c+2], sacc[c/6]);
          sacc[c/6] = fmaf(bfhi(w.y), qkv[4*c+3], sacc[c/6]);
        }
        #pragma unroll
        for (int hh = 0; hh < 8; ++hh) cprob[hh][t] = sacc[hh]*scl;
      }
      __syncthreads();
      // --- CA softmax over 128 (wave = head) ---
      {
        float s0 = cprob[wv][lane], s1 = cprob[wv][lane+64];
        float m = fmaxf(s0, s1);
        #pragma unroll
        for (int o2 = 32; o2; o2 >>= 1) m = fmaxf(m, __shfl_xor(m, o2, 64));
        float e0 = __expf(s0-m), e1 = __expf(s1-m);
        float sm = e0+e1;
        #pragma unroll
        for (int o2 = 32; o2; o2 >>= 1) sm += __shfl_xor(sm, o2, 64);
        cprob[wv][lane] = e0; cprob[wv][lane+64] = e1;
        if (lane == 0) cainv[wv] = 1.0f / sm;
      }
      __syncthreads();
      // --- CA PV (split over j halves; coalesced V rows) ---
      if (t < 384) {
        int half = (t >= 192), tm = t - 192*half;
        int hh = tm / 24;
        const u16* vb = kvb + ((size_t)l*NNODES + (size_t)b*NPG_)*384 + 192 + tm;
        float a = 0.f;
        for (int j = half*64; j < half*64 + 64; ++j)
          a = fmaf(cprob[hh][j], bfu(vb[(size_t)j*384]), a);
        ps[half][tm] = a;
      }
      __syncthreads();
      if (t < DM) attno[t] = (ps[0][t] + ps[1][t]) * cainv[t/24];
      __syncthreads();
      // --- CA out + residual + LN ---
      skgemv(WL + OFF_CAO, caoutb + l*DM, attno, ps, t);
      __syncthreads();
      if (t < DM) y[t] = x[t] + ps[0][t] + ps[1][t];
      __syncthreads();
      ln512(y, x, t, lng + (l*3+1)*DM, lnb + (l*3+1)*DM, red);
      // --- FF1: N=512 K=192 ---
      {
        const uint2* col = WL + OFF_FF1 + t;
        float a = ff1b[l*DFF_ + t];
        #pragma unroll 16
        for (int kq = 0; kq < 48; ++kq) fma4(a, col[(size_t)kq*512], x + 4*kq);
        hid[t] = gelu_f(a);
      }
      __syncthreads();
      // --- FF2: N=192 K=512 split-K2 ---
      if (t < 384) {
        int ks = (t >= 192), o = t - 192*ks;
        const uint2* col = WL + OFF_FF2 + o;
        float a = ks ? 0.f : ff2b[l*DM + o];
        #pragma unroll 16
        for (int kq2 = 0; kq2 < 64; ++kq2) {
          int kq = ks*64 + kq2;
          fma4(a, col[(size_t)kq*192], hid + 4*kq);
        }
        ps[ks][o] = a;
      }
      __syncthreads();
      if (t < DM) y[t] = x[t] + ps[0][t] + ps[1][t];
      __syncthreads();
      ln512(y, x, t, lng + (l*3+2)*DM, lnb + (l*3+2)*DM, red);
    }
    // --- head: h1 (gelu) -> h2 -> feats ; lasts ; adjacency ---
    skgemv(wp + OFF_H1, h1b, x, ps, t);
    __syncthreads();
    if (t < DM) { hid[t] = gelu_f(ps[0][t] + ps[1][t]); lasts[i][t] = x[t]; }
    __syncthreads();
    if (t < 256) {
      const uint2* col = wp + OFF_H2 + t;
      float a = h2b[t];
      #pragma unroll 16
      for (int kq = 0; kq < 48; ++kq) fma4(a, col[(size_t)kq*256], hid + 4*kq);
      feats[((size_t)b*PP + i)*256 + t] = a;
    }
    if (t <= i) {
      float a = 0.f;
      for (int d = 0; d < DM; ++d) a = fmaf(lasts[t][d], lasts[i][d], a);
      if (t == 0) {
        adj[((size_t)b*SM + i)*SM + 32] = a;
        adj[((size_t)b*SM + 32)*SM + i] = a;
      } else {
        int j2 = t - 1;
        adj[((size_t)b*SM + j2)*SM + i] = a;
        adj[((size_t)b*SM + i)*SM + j2] = a;
      }
    }
    __syncthreads();
  }
}

// ---------------- launch ----------------
extern "C" void kernel_launch(void* const* d_in, const int* in_sizes, int n_in,
                              void* d_out, int out_size, void* d_ws, size_t ws_size,
                              hipStream_t stream) {
  (void)in_sizes; (void)n_in; (void)out_size; (void)ws_size;
  const float* x_in    = (const float*)d_in[0];
  const int*   ei      = (const int*)d_in[1];
  const int*   tgt_idx = (const int*)d_in[2];
  const float* gat1_w  = (const float*)d_in[5];
  const float* g1as    = (const float*)d_in[6];
  const float* g1ad    = (const float*)d_in[7];
  const float* g1b     = (const float*)d_in[8];
  const float* gat2_w  = (const float*)d_in[9];
  const float* g2as    = (const float*)d_in[10];
  const float* g2ad    = (const float*)d_in[11];
  const float* g2b     = (const float*)d_in[12];
  const float* saqkvw  = (const float*)d_in[13];
  const float* saqkvb  = (const float*)d_in[14];
  const float* saoutw  = (const float*)d_in[15];
  const float* saoutb  = (const float*)d_in[16];
  const float* caqkvw  = (const float*)d_in[17];
  const float* caqkvb  = (const float*)d_in[18];
  const float* caoutw  = (const float*)d_in[19];
  const float* caoutb  = (const float*)d_in[20];
  const float* ff1w    = (const float*)d_in[21];
  const float* ff1b    = (const float*)d_in[22];
  const float* ff2w    = (const float*)d_in[23];
  const float* ff2b    = (const float*)d_in[24];
  const float* lng     = (const float*)d_in[25];
  const float* lnb     = (const float*)d_in[26];
  const float* h1w     = (const float*)d_in[27];
  const float* h1b     = (const float*)d_in[28];
  const float* h2w     = (const float*)d_in[29];
  const float* h2b     = (const float*)d_in[30];

  float* ws  = (float*)d_ws;
  float* out = (float*)d_out;
  float* adj = out + (size_t)BZ*PP*256;

  const int* src = ei;
  const int* dst = ei + NEDGE;

  int* cnt  = (int*)(ws + O_CNT);
  int* base = (int*)(ws + O_BASE);
  int* fill = (int*)(ws + O_FILL);
  int* csrc = (int*)(ws + O_CSRC);

  hipLaunchKernelGGL(zero_kernel, dim3(545), dim3(256), 0, stream, adj, cnt, fill);

  // ---- GAT1 ----
  hipLaunchKernelGGL((gemm_nt<false,false>), dim3(C1/64, NNODES/64), dim3(256), 0, stream,
                     x_in, gat1_w, (const float*)nullptr, ws + O_XP1, (__hip_bfloat16*)nullptr,
                     NNODES, C1, FIN);
  hipLaunchKernelGGL((al_kernel<4,96>), dim3(NNODES*4/256), dim3(256), 0, stream,
                     ws+O_XP1, g1as, g1ad, ws+O_AL1S, ws+O_AL1D);
  hipLaunchKernelGGL(count_kernel, dim3(NEDGE/256), dim3(256), 0, stream, dst, cnt);
  hipLaunchKernelGGL(scan_kernel, dim3(1), dim3(1024), 0, stream, cnt, base);
  hipLaunchKernelGGL(scatter_kernel, dim3(NEL/256), dim3(256), 0, stream, src, dst, base, fill, csrc);
  hipLaunchKernelGGL((agg_kernel<4,96,true>), dim3(NNODES), dim3(128), 0, stream,
                     ws+O_XP1, ws+O_AL1S, ws+O_AL1D, cnt, base, csrc, g1b, ws+O_H);

  // ---- GAT2 ----
  hipLaunchKernelGGL((gemm_nt<false,false>), dim3(DM/64, NNODES/64), dim3(256), 0, stream,
                     ws+O_H, gat2_w, (const float*)nullptr, ws+O_XP2, (__hip_bfloat16*)nullptr,
                     NNODES, DM, C1);
  hipLaunchKernelGGL((al_kernel<1,192>), dim3(NNODES/256), dim3(256), 0, stream,
                     ws+O_XP2, g2as, g2ad, ws+O_AL2S, ws+O_AL2D);
  hipLaunchKernelGGL((agg_kernel<1,192,false>), dim3(NNODES), dim3(128), 0, stream,
                     ws+O_XP2, ws+O_AL2S, ws+O_AL2D, cnt, base, csrc, g2b, ws+O_MEM);

  // ---- pack decode weights to bf16 [K/4][N] uint2 ----
  uint2* wp = (uint2*)(ws + O_WP);
  auto PK = [&](const float* Wsrc, int off_u2, int N, int K) {
    hipLaunchKernelGGL(pack_kernel, dim3((N*(K/4)+255)/256), dim3(256), 0, stream,
                       Wsrc, wp + off_u2, N, K);
  };
  for (int l = 0; l < LL; ++l) {
    PK(saqkvw + (size_t)l*110592, l*PL2 + OFF_QKV, 576, 192);
    PK(saoutw + (size_t)l*36864,  l*PL2 + OFF_SAO, 192, 192);
    PK(caqkvw + (size_t)l*110592, l*PL2 + OFF_CAQ, 192, 192);  // first 192 rows = Wq
    PK(caoutw + (size_t)l*36864,  l*PL2 + OFF_CAO, 192, 192);
    PK(ff1w   + (size_t)l*98304,  l*PL2 + OFF_FF1, 512, 192);
    PK(ff2w   + (size_t)l*98304,  l*PL2 + OFF_FF2, 192, 512);
  }
  PK(h1w, OFF_H1, 192, 192);
  PK(h2w, OFF_H2, 256, 192);

  hipLaunchKernelGGL(pe_kernel, dim3((SM*DM+255)/256), dim3(256), 0, stream, ws+O_PE);

  // ---- CA K/V hoisted: KV[l] = mem @ [Wk;Wv]^T + [bk;bv] (bf16; overlaps dead xp1/h) ----
  __hip_bfloat16* kvb = (__hip_bfloat16*)ws;
  for (int l = 0; l < LL; ++l) {
    hipLaunchKernelGGL((gemm_nt<true,true>), dim3(384/64, NNODES/64), dim3(256), 0, stream,
                       ws+O_MEM, caqkvw + (size_t)l*110592 + (size_t)192*192,
                       caqkvb + l*576 + 192, (float*)nullptr,
                       kvb + (size_t)l*NNODES*384, NNODES, 384, DM);
  }

  hipLaunchKernelGGL(decode_kernel, dim3(BZ), dim3(512), 0, stream,
                     ws+O_MEM, (const u16*)kvb, wp, ws+O_PE, (u32*)(ws+O_VSA), tgt_idx,
                     saqkvb, saoutb, caqkvb, caoutb, ff1b, ff2b, lng, lnb, h1b, h2b,
                     out, adj);
}

// Round 3
// 8436.208 us; speedup vs baseline: 1.3415x; 1.3415x over previous
//
#include <hip/hip_runtime.h>
#include <hip/hip_bf16.h>
#include <math.h>

#define DEV __device__ __forceinline__
typedef unsigned int u32;
typedef unsigned short u16;
typedef u32 __attribute__((ext_vector_type(4))) u32x4;

constexpr int NNODES = 16384;
constexpr int NEDGE  = 262144;
constexpr int NEL    = NEDGE + NNODES;
constexpr int FIN    = 256;
constexpr int C1     = 384;
constexpr int DM     = 192;
constexpr int BZ     = 128;
constexpr int NPG_   = 128;
constexpr int LL     = 4;
constexpr int PP     = 32;
constexpr int SM     = 33;
constexpr int DFF_   = 512;

// packed-weight layout (uint4 units, [K/8][N]) per layer
constexpr int PL4     = 52224;
constexpr int OFF4_QKV = 0;        // 576x192 -> 24*576
constexpr int OFF4_SAO = 13824;    // 192x192 -> 24*192
constexpr int OFF4_CAQ = 18432;
constexpr int OFF4_CAO = 23040;
constexpr int OFF4_FF1 = 27648;    // 512x192 -> 24*512
constexpr int OFF4_FF2 = 39936;    // 192x512 -> 64*192
constexpr int OFF4_H1  = 4*PL4;           // 208896
constexpr int OFF4_H2  = OFF4_H1 + 4608;  // 213504 ; +6144 -> 219648 u4 total

// ---- workspace layout (float units) ----
constexpr size_t O_XP1 = 0;                       // later overlapped by bf16 CA-KV
constexpr size_t O_H   = 6291456;
constexpr size_t O_XP2 = 12582912;
constexpr size_t O_MEM = 15728640;
constexpr size_t O_VSA = 18874368;                // SA V cache (u32 units): 128*4*33*96
constexpr size_t O_WP  = 20496384;                // packed weights: 219648 u4 = 878592 floats
constexpr size_t O_PE  = 21374976;
constexpr size_t O_AL1S= O_PE + 6336;
constexpr size_t O_AL1D= O_AL1S + 65536;
constexpr size_t O_AL2S= O_AL1D + 65536;
constexpr size_t O_AL2D= O_AL2S + 16384;
constexpr size_t O_CNT = O_AL2D + 16384;
constexpr size_t O_BASE= O_CNT + 16384;
constexpr size_t O_FILL= O_BASE + 16384;
constexpr size_t O_CSRC= O_FILL + 16384;

DEV float gelu_f(float v) { return 0.5f*v*(1.0f + erff(v*0.7071067811865475f)); }
DEV float bflo(u32 w) { return __uint_as_float(w << 16); }
DEV float bfhi(u32 w) { return __uint_as_float(w & 0xffff0000u); }
DEV float bfu(u16 u)  { return __uint_as_float(((u32)u) << 16); }
DEV u32 pk2(float a, float b) {
  __hip_bfloat16 ha = __float2bfloat16(a), hb = __float2bfloat16(b);
  u32 ua = *reinterpret_cast<u16*>(&ha), ub = *reinterpret_cast<u16*>(&hb);
  return ua | (ub << 16);
}
DEV uint4 ntload4(const void* p) {
  u32x4 v = __builtin_nontemporal_load((const u32x4*)p);
  uint4 r; r.x = v.x; r.y = v.y; r.z = v.z; r.w = v.w; return r;
}
DEV void fma8(float& a, uint4 w, float4 xa, float4 xb) {
  a = fmaf(bflo(w.x), xa.x, a); a = fmaf(bfhi(w.x), xa.y, a);
  a = fmaf(bflo(w.y), xa.z, a); a = fmaf(bfhi(w.y), xa.w, a);
  a = fmaf(bflo(w.z), xb.x, a); a = fmaf(bfhi(w.z), xb.y, a);
  a = fmaf(bflo(w.w), xb.z, a); a = fmaf(bfhi(w.w), xb.w, a);
}
// dot of one weight column (NU4 u4 rows, row stride STRIDE u4) with xv; 4 accumulators
template<int NU4, int STRIDE>
DEV float dotcol(const uint4* __restrict__ col, const float* __restrict__ xv) {
  const float4* x4 = (const float4*)xv;
  float a0 = 0, a1 = 0, a2 = 0, a3 = 0;
  #pragma unroll
  for (int q = 0; q < NU4; q += 4) {
    uint4 w0 = col[(q+0)*STRIDE];
    uint4 w1 = col[(q+1)*STRIDE];
    uint4 w2 = col[(q+2)*STRIDE];
    uint4 w3 = col[(q+3)*STRIDE];
    fma8(a0, w0, x4[2*q+0], x4[2*q+1]);
    fma8(a1, w1, x4[2*q+2], x4[2*q+3]);
    fma8(a2, w2, x4[2*q+4], x4[2*q+5]);
    fma8(a3, w3, x4[2*q+6], x4[2*q+7]);
  }
  return (a0+a1)+(a2+a3);
}

// ---------------- misc ----------------
__global__ void zero_kernel(float* adj, int* cnt, int* fill) {
  int i = blockIdx.x*256 + threadIdx.x;
  if (i < BZ*SM*SM) adj[i] = 0.f;
  if (i < NNODES) { cnt[i] = 0; fill[i] = 0; }
}

__global__ void pe_kernel(float* pe) {
  int idx = blockIdx.x*256 + threadIdx.x;
  if (idx >= SM*DM) return;
  int p = idx / DM, d = idx % DM;
  int i2 = d >> 1;
  float div = __expf((float)(2*i2) * (-9.210340371976184f / (float)DM));
  float a = (float)p * div;
  pe[idx] = (d & 1) ? cosf(a) : sinf(a);
}

// pack W[N][K] fp32 -> P[kq*N+o] = 8 bf16 of W[o][8kq..8kq+7]
__global__ void pack_kernel(const float* __restrict__ W, uint4* __restrict__ P, int N, int K) {
  int idx = blockIdx.x*256 + threadIdx.x;
  if (idx >= N*(K>>3)) return;
  int o = idx % N, kq = idx / N;
  const float* r = W + (size_t)o*K + 8*kq;
  uint4 u;
  u.x = pk2(r[0], r[1]); u.y = pk2(r[2], r[3]);
  u.z = pk2(r[4], r[5]); u.w = pk2(r[6], r[7]);
  P[idx] = u;
}

// ---------------- generic fp32 GEMM: C[M,N] = A[M,K] @ W[N,K]^T (+bias) ----------------
template<bool BIAS, bool BF16OUT>
__global__ __launch_bounds__(256) void gemm_nt(const float* __restrict__ A,
    const float* __restrict__ W, const float* __restrict__ bias,
    float* __restrict__ Cf, __hip_bfloat16* __restrict__ Cb, int M, int N, int K)
{
  __shared__ float As[16][68];
  __shared__ float Ws[16][68];
  const int bm = blockIdx.y*64, bn = blockIdx.x*64;
  const int t = threadIdx.x, tx = t & 15, ty = t >> 4;
  float acc[4][4] = {};
  for (int k0 = 0; k0 < K; k0 += 16) {
    #pragma unroll
    for (int i = 0; i < 4; ++i) {
      int idx = t + i*256, kk = idx & 15, m = idx >> 4;
      As[kk][m] = A[(size_t)(bm+m)*K + k0+kk];
      Ws[kk][m] = W[(size_t)(bn+m)*K + k0+kk];
    }
    __syncthreads();
    #pragma unroll
    for (int kk = 0; kk < 16; ++kk) {
      const float4 a4 = *(const float4*)&As[kk][ty*4];
      const float4 b4 = *(const float4*)&Ws[kk][tx*4];
      const float av[4] = {a4.x,a4.y,a4.z,a4.w};
      const float bv[4] = {b4.x,b4.y,b4.z,b4.w};
      #pragma unroll
      for (int i = 0; i < 4; ++i)
        #pragma unroll
        for (int j = 0; j < 4; ++j)
          acc[i][j] = fmaf(av[i], bv[j], acc[i][j]);
    }
    __syncthreads();
  }
  #pragma unroll
  for (int i = 0; i < 4; ++i) {
    const int m = bm + ty*4 + i;
    #pragma unroll
    for (int j = 0; j < 4; ++j) {
      const int n = bn + tx*4 + j;
      float v = acc[i][j];
      if (BIAS) v += bias[n];
      if (BF16OUT) Cb[(size_t)m*N + n] = __float2bfloat16(v);
      else         Cf[(size_t)m*N + n] = v;
    }
  }
}

// ---------------- GAT helpers ----------------
template<int HEADS, int CH>
__global__ void al_kernel(const float* __restrict__ xp, const float* __restrict__ asrc,
                          const float* __restrict__ adst, float* als, float* ald) {
  int idx = blockIdx.x*256 + threadIdx.x;
  if (idx >= NNODES*HEADS) return;
  int n = idx / HEADS, h = idx % HEADS;
  const float* row = xp + (size_t)n*(HEADS*CH) + h*CH;
  float s = 0, d = 0;
  for (int c = 0; c < CH; ++c) { float v = row[c]; s = fmaf(v, asrc[h*CH+c], s); d = fmaf(v, adst[h*CH+c], d); }
  als[idx] = s; ald[idx] = d;
}

__global__ void count_kernel(const int* __restrict__ dst, int* cnt) {
  int e = blockIdx.x*256 + threadIdx.x;
  if (e < NEDGE) atomicAdd(&cnt[dst[e]], 1);
}

__global__ __launch_bounds__(1024) void scan_kernel(const int* __restrict__ cnt, int* base) {
  __shared__ int tot[1024];
  int t = threadIdx.x;
  int local[16]; int s = 0;
  #pragma unroll
  for (int i = 0; i < 16; ++i) { int v = cnt[t*16+i] + 1; local[i] = s; s += v; }
  tot[t] = s; __syncthreads();
  if (t == 0) { int r = 0; for (int i = 0; i < 1024; ++i) { int v = tot[i]; tot[i] = r; r += v; } }
  __syncthreads();
  int off = tot[t];
  #pragma unroll
  for (int i = 0; i < 16; ++i) base[t*16+i] = off + local[i];
}

__global__ void scatter_kernel(const int* __restrict__ src, const int* __restrict__ dst,
                               const int* __restrict__ base, int* fill, int* csrc) {
  int e = blockIdx.x*256 + threadIdx.x;
  if (e < NEDGE) {
    int d = dst[e];
    int p = atomicAdd(&fill[d], 1);
    csrc[base[d] + p] = src[e];
  } else if (e < NEL) {
    int n = e - NEDGE;
    int p = atomicAdd(&fill[n], 1);
    csrc[base[n] + p] = n;
  }
}

template<int HEADS, int CH, bool ELU>
__global__ __launch_bounds__(128) void agg_kernel(const float* __restrict__ xp,
    const float* __restrict__ als, const float* __restrict__ ald,
    const int* __restrict__ cnt, const int* __restrict__ base, const int* __restrict__ csrc,
    const float* __restrict__ bias, float* __restrict__ out)
{
  constexpr int CO = HEADS*CH;
  constexpr int MAXD = 128;
  int n = blockIdx.x, t = threadIdx.x;
  int deg = cnt[n] + 1, st = base[n];
  if (deg > MAXD) deg = MAXD;
  __shared__ int   srcs[MAXD];
  __shared__ float ex[MAXD][HEADS];
  __shared__ float den[HEADS];
  for (int j = t; j < deg; j += 128) srcs[j] = csrc[st + j];
  __syncthreads();
  for (int idx = t; idx < deg*HEADS; idx += 128) {
    int j = idx / HEADS, h = idx % HEADS;
    float e = als[srcs[j]*HEADS + h] + ald[n*HEADS + h];
    ex[j][h] = (e > 0.f) ? e : 0.2f*e;
  }
  __syncthreads();
  if (t < HEADS) {
    float m = -1e30f;
    for (int j = 0; j < deg; ++j) m = fmaxf(m, ex[j][t]);
    float s = 0;
    for (int j = 0; j < deg; ++j) { float v = __expf(ex[j][t]-m); ex[j][t] = v; s += v; }
    den[t] = 1.0f/(s + 1e-16f);
  }
  __syncthreads();
  for (int c = t; c < CO; c += 128) {
    int h = c / CH;
    float acc = 0;
    for (int j = 0; j < deg; ++j) acc = fmaf(ex[j][h], xp[(size_t)srcs[j]*CO + c], acc);
    float v = acc*den[h] + bias[c];
    if (ELU) v = (v > 0.f) ? v : (__expf(v) - 1.0f);
    out[(size_t)n*CO + c] = v;
  }
}

// ---------------- decode ----------------
__global__ __launch_bounds__(512, 1) void decode_kernel(
    const float* __restrict__ mem, const u16* __restrict__ kvb,
    const uint4* __restrict__ wp, const float* __restrict__ pe,
    u32* __restrict__ vsa, const int* __restrict__ tgt_idx,
    const float* __restrict__ saqkvb, const float* __restrict__ saoutb,
    const float* __restrict__ caqkvb, const float* __restrict__ caoutb,
    const float* __restrict__ ff1b, const float* __restrict__ ff2b,
    const float* __restrict__ lng, const float* __restrict__ lnb,
    const float* __restrict__ h1b, const float* __restrict__ h2b,
    float* __restrict__ feats, float* __restrict__ adj)
{
  const int b = blockIdx.x, t = threadIdx.x;
  const int wv = t >> 6, lane = t & 63;
  __shared__ u32   ksa[4*33*97];         // SA K cache bf16x2, odd dword stride
  __shared__ u16   Vlds[192*130];        // CA V slab, transposed [dim][node], stride 130
  __shared__ float lasts[SM][193];
  __shared__ __align__(16) float x[DM];
  __shared__ __align__(16) float qkv[3*DM];
  __shared__ __align__(16) float attno[DM];
  __shared__ __align__(16) float hid[DFF_];
  __shared__ float prob[32*9];           // [key][9] odd stride
  __shared__ float cprob[128*9];
  __shared__ float ps[2][DM];
  __shared__ float painv[8], cainv[8], red[16];
  const float scl = 0.2041241452319315f; // 1/sqrt(24)
  const float* tgt0 = mem + ((size_t)b*NPG_ + tgt_idx[b])*DM;
  const uint4* kvb4 = (const uint4*)kvb;

  // fused residual(+partials)+LayerNorm: x <- LN(x + ps0 + ps1)
  auto ln_ps = [&](const float* g, const float* be) {
    float v = 0.f;
    if (t < DM) v = x[t] + ps[0][t] + ps[1][t];
    float s = v, q = v*v;
    #pragma unroll
    for (int o = 32; o; o >>= 1) { s += __shfl_down(s, o, 64); q += __shfl_down(q, o, 64); }
    if (lane == 0) { red[wv] = s; red[8+wv] = q; }
    __syncthreads();
    float S = 0, Q = 0;
    #pragma unroll
    for (int w = 0; w < 8; ++w) { S += red[w]; Q += red[8+w]; }
    float mu = S*(1.f/DM), var = Q*(1.f/DM) - mu*mu;
    float rstd = rsqrtf(var + 1e-5f);
    if (t < DM) x[t] = (v-mu)*rstd*g[t] + be[t];
    __syncthreads();
  };
  // split-K2 GEMV N=192 K=192 -> ps
  auto skgemv2 = [&](const uint4* P, const float* bias) {
    if (t < 384) {
      int ks = t >= 192, o = t - 192*ks;
      float a = dotcol<12,192>(P + ks*12*192 + o, x + 96*ks);
      ps[ks][o] = a + (ks ? 0.f : bias[o]);
    }
  };
  auto skgemv2v = [&](const uint4* P, const float* bias, const float* xv) {
    if (t < 384) {
      int ks = t >= 192, o = t - 192*ks;
      float a = dotcol<12,192>(P + ks*12*192 + o, xv + 96*ks);
      ps[ks][o] = a + (ks ? 0.f : bias[o]);
    }
  };

  for (int i = 0; i < PP; ++i) {
    if (t < DM) x[t] = ((i == 0) ? tgt0[t] : lasts[i-1][t]) + pe[i*DM + t];
    __syncthreads();
    for (int l = 0; l < LL; ++l) {
      const uint4* WL = wp + (size_t)l*PL4;
      // --- SA qkv: 576 cols, K=192 ---
      for (int o = t; o < 576; o += 512)
        qkv[o] = saqkvb[l*576 + o] + dotcol<24,576>(WL + OFF4_QKV + o, x);
      __syncthreads();
      // --- store K (LDS) / V (global) caches ---
      if (t < 96) vsa[(((size_t)b*LL + l)*SM + i)*96 + t] = pk2(qkv[384+2*t], qkv[385+2*t]);
      else if (t < 192) { int d2 = t-96; ksa[l*3201 + i*97 + d2] = pk2(qkv[192+2*d2], qkv[193+2*d2]); }
      __syncthreads();
      // --- stage CA V slab -> LDS transposed (NT loads) ---
      for (int u = t; u < 128*24; u += 512) {
        int node = u / 24, q2 = u % 24;
        uint4 w = ntload4(kvb4 + ((size_t)l*NNODES + (size_t)b*NPG_ + node)*48 + 24 + q2);
        u32 wa[4] = {w.x, w.y, w.z, w.w};
        #pragma unroll
        for (int e = 0; e < 4; ++e) {
          Vlds[(q2*8 + 2*e)*130 + node]   = (u16)(wa[e] & 0xffffu);
          Vlds[(q2*8 + 2*e+1)*130 + node] = (u16)(wa[e] >> 16);
        }
      }
      // --- SA QK^T + softmax (wave = head, lane = key) ---
      {
        float s = -1e30f;
        if (lane <= i) {
          const u32* kr = ksa + l*3201 + lane*97 + wv*12;
          float a0 = 0, a1 = 0;
          #pragma unroll
          for (int c = 0; c < 12; c += 2) {
            u32 w0 = kr[c], w1 = kr[c+1];
            a0 = fmaf(bflo(w0), qkv[wv*24 + 2*c],   a0);
            a0 = fmaf(bfhi(w0), qkv[wv*24 + 2*c+1], a0);
            a1 = fmaf(bflo(w1), qkv[wv*24 + 2*c+2], a1);
            a1 = fmaf(bfhi(w1), qkv[wv*24 + 2*c+3], a1);
          }
          s = (a0+a1) * scl;
        }
        float m = s;
        #pragma unroll
        for (int o2 = 32; o2; o2 >>= 1) m = fmaxf(m, __shfl_xor(m, o2, 64));
        float e = (lane <= i) ? __expf(s - m) : 0.f;
        float sm = e;
        #pragma unroll
        for (int o2 = 32; o2; o2 >>= 1) sm += __shfl_xor(sm, o2, 64);
        if (lane <= i) prob[lane*9 + wv] = e;
        if (lane == 0) painv[wv] = 1.0f / sm;
      }
      __syncthreads();
      // --- SA PV ---
      if (t < DM) {
        int hh = t / 24;
        const u16* vb = (const u16*)vsa + (((size_t)b*LL + l)*SM)*192 + t;
        float a0 = 0, a1 = 0;
        for (int j = 0; j + 1 <= i; j += 2) {
          a0 = fmaf(prob[j*9 + hh],     bfu(vb[(size_t)j*192]),     a0);
          a1 = fmaf(prob[(j+1)*9 + hh], bfu(vb[(size_t)(j+1)*192]), a1);
        }
        if (!(i & 1)) a0 = fmaf(prob[i*9 + hh], bfu(vb[(size_t)i*192]), a0);
        attno[t] = (a0 + a1) * painv[hh];
      }
      __syncthreads();
      // --- SA out + residual + LN ---
      skgemv2v(WL + OFF4_SAO, saoutb + l*DM, attno);
      __syncthreads();
      ln_ps(lng + (l*3+0)*DM, lnb + (l*3+0)*DM);
      // --- CA q ---
      skgemv2(WL + OFF4_CAQ, caqkvb + l*3*DM);
      __syncthreads();
      if (t < DM) qkv[t] = ps[0][t] + ps[1][t];
      __syncthreads();
      // --- CA QK^T: 1024 (key,head) scores over 512 threads (NT K loads) ---
      for (int s2 = t; s2 < 1024; s2 += 512) {
        int j = s2 >> 3, hh = s2 & 7;
        const uint4* kr = kvb4 + ((size_t)l*NNODES + (size_t)b*NPG_ + j)*48 + hh*3;
        uint4 w0 = ntload4(kr), w1 = ntload4(kr+1), w2 = ntload4(kr+2);
        const float4* q4 = (const float4*)qkv + hh*6;
        float a0 = 0, a1 = 0, a2 = 0;
        fma8(a0, w0, q4[0], q4[1]);
        fma8(a1, w1, q4[2], q4[3]);
        fma8(a2, w2, q4[4], q4[5]);
        cprob[j*9 + hh] = (a0+a1+a2) * scl;
      }
      __syncthreads();
      // --- CA softmax over 128 keys (wave = head) ---
      {
        float s0 = cprob[lane*9 + wv], s1 = cprob[(lane+64)*9 + wv];
        float m = fmaxf(s0, s1);
        #pragma unroll
        for (int o2 = 32; o2; o2 >>= 1) m = fmaxf(m, __shfl_xor(m, o2, 64));
        float e0 = __expf(s0-m), e1 = __expf(s1-m);
        float sm = e0+e1;
        #pragma unroll
        for (int o2 = 32; o2; o2 >>= 1) sm += __shfl_xor(sm, o2, 64);
        cprob[lane*9 + wv] = e0; cprob[(lane+64)*9 + wv] = e1;
        if (lane == 0) cainv[wv] = 1.0f / sm;
      }
      __syncthreads();
      // --- CA PV from LDS V slab (conflict-free: odd dword stride per dim-row) ---
      if (t < 384) {
        int half = t / 192, tm = t - 192*half, hh = tm / 24;
        const u16* vr = Vlds + tm*130 + half*64;
        int jb = half*64;
        float a0 = 0, a1 = 0;
        #pragma unroll
        for (int j = 0; j < 64; j += 2) {
          a0 = fmaf(cprob[(jb+j)*9 + hh],   bfu(vr[j]),   a0);
          a1 = fmaf(cprob[(jb+j+1)*9 + hh], bfu(vr[j+1]), a1);
        }
        ps[half][tm] = a0 + a1;
      }
      __syncthreads();
      if (t < DM) attno[t] = (ps[0][t] + ps[1][t]) * cainv[t/24];
      __syncthreads();
      // --- CA out + residual + LN ---
      skgemv2v(WL + OFF4_CAO, caoutb + l*DM, attno);
      __syncthreads();
      ln_ps(lng + (l*3+1)*DM, lnb + (l*3+1)*DM);
      // --- FF1: 512 cols K=192 ---
      hid[t] = gelu_f(ff1b[l*DFF_ + t] + dotcol<24,512>(WL + OFF4_FF1 + t, x));
      __syncthreads();
      // --- FF2: 192 cols K=512 split-K2 ---
      if (t < 384) {
        int ks = t >= 192, o = t - 192*ks;
        float a = dotcol<32,192>(WL + OFF4_FF2 + ks*32*192 + o, hid + 256*ks);
        ps[ks][o] = a + (ks ? 0.f : ff2b[l*DM + o]);
      }
      __syncthreads();
      ln_ps(lng + (l*3+2)*DM, lnb + (l*3+2)*DM);
    }
    // --- head: h1(gelu) -> h2 -> feats ; lasts ; adjacency ---
    skgemv2(wp + OFF4_H1, h1b);
    __syncthreads();
    if (t < DM) { hid[t] = gelu_f(ps[0][t] + ps[1][t]); lasts[i][t] = x[t]; }
    __syncthreads();
    if (t < 256)
      feats[((size_t)b*PP + i)*256 + t] = h2b[t] + dotcol<24,256>(wp + OFF4_H2 + t, hid);
    if (t <= i) {
      float a = 0.f;
      for (int d = 0; d < DM; ++d) a = fmaf(lasts[t][d], lasts[i][d], a);
      if (t == 0) {
        adj[((size_t)b*SM + i)*SM + 32] = a;
        adj[((size_t)b*SM + 32)*SM + i] = a;
      } else {
        int j2 = t - 1;
        adj[((size_t)b*SM + j2)*SM + i] = a;
        adj[((size_t)b*SM + i)*SM + j2] = a;
      }
    }
    __syncthreads();
  }
}

// ---------------- launch ----------------
extern "C" void kernel_launch(void* const* d_in, const int* in_sizes, int n_in,
                              void* d_out, int out_size, void* d_ws, size_t ws_size,
                              hipStream_t stream) {
  (void)in_sizes; (void)n_in; (void)out_size; (void)ws_size;
  const float* x_in    = (const float*)d_in[0];
  const int*   ei      = (const int*)d_in[1];
  const int*   tgt_idx = (const int*)d_in[2];
  const float* gat1_w  = (const float*)d_in[5];
  const float* g1as    = (const float*)d_in[6];
  const float* g1ad    = (const float*)d_in[7];
  const float* g1b     = (const float*)d_in[8];
  const float* gat2_w  = (const float*)d_in[9];
  const float* g2as    = (const float*)d_in[10];
  const float* g2ad    = (const float*)d_in[11];
  const float* g2b     = (const float*)d_in[12];
  const float* saqkvw  = (const float*)d_in[13];
  const float* saqkvb  = (const float*)d_in[14];
  const float* saoutw  = (const float*)d_in[15];
  const float* saoutb  = (const float*)d_in[16];
  const float* caqkvw  = (const float*)d_in[17];
  const float* caqkvb  = (const float*)d_in[18];
  const float* caoutw  = (const float*)d_in[19];
  const float* caoutb  = (const float*)d_in[20];
  const float* ff1w    = (const float*)d_in[21];
  const float* ff1b    = (const float*)d_in[22];
  const float* ff2w    = (const float*)d_in[23];
  const float* ff2b    = (const float*)d_in[24];
  const float* lng     = (const float*)d_in[25];
  const float* lnb     = (const float*)d_in[26];
  const float* h1w     = (const float*)d_in[27];
  const float* h1b     = (const float*)d_in[28];
  const float* h2w     = (const float*)d_in[29];
  const float* h2b     = (const float*)d_in[30];

  float* ws  = (float*)d_ws;
  float* out = (float*)d_out;
  float* adj = out + (size_t)BZ*PP*256;

  const int* src = ei;
  const int* dst = ei + NEDGE;

  int* cnt  = (int*)(ws + O_CNT);
  int* base = (int*)(ws + O_BASE);
  int* fill = (int*)(ws + O_FILL);
  int* csrc = (int*)(ws + O_CSRC);

  hipLaunchKernelGGL(zero_kernel, dim3(545), dim3(256), 0, stream, adj, cnt, fill);

  // ---- GAT1 ----
  hipLaunchKernelGGL((gemm_nt<false,false>), dim3(C1/64, NNODES/64), dim3(256), 0, stream,
                     x_in, gat1_w, (const float*)nullptr, ws + O_XP1, (__hip_bfloat16*)nullptr,
                     NNODES, C1, FIN);
  hipLaunchKernelGGL((al_kernel<4,96>), dim3(NNODES*4/256), dim3(256), 0, stream,
                     ws+O_XP1, g1as, g1ad, ws+O_AL1S, ws+O_AL1D);
  hipLaunchKernelGGL(count_kernel, dim3(NEDGE/256), dim3(256), 0, stream, dst, cnt);
  hipLaunchKernelGGL(scan_kernel, dim3(1), dim3(1024), 0, stream, cnt, base);
  hipLaunchKernelGGL(scatter_kernel, dim3(NEL/256), dim3(256), 0, stream, src, dst, base, fill, csrc);
  hipLaunchKernelGGL((agg_kernel<4,96,true>), dim3(NNODES), dim3(128), 0, stream,
                     ws+O_XP1, ws+O_AL1S, ws+O_AL1D, cnt, base, csrc, g1b, ws+O_H);

  // ---- GAT2 ----
  hipLaunchKernelGGL((gemm_nt<false,false>), dim3(DM/64, NNODES/64), dim3(256), 0, stream,
                     ws+O_H, gat2_w, (const float*)nullptr, ws+O_XP2, (__hip_bfloat16*)nullptr,
                     NNODES, DM, C1);
  hipLaunchKernelGGL((al_kernel<1,192>), dim3(NNODES/256), dim3(256), 0, stream,
                     ws+O_XP2, g2as, g2ad, ws+O_AL2S, ws+O_AL2D);
  hipLaunchKernelGGL((agg_kernel<1,192,false>), dim3(NNODES), dim3(128), 0, stream,
                     ws+O_XP2, ws+O_AL2S, ws+O_AL2D, cnt, base, csrc, g2b, ws+O_MEM);

  // ---- pack decode weights to bf16 [K/8][N] uint4 ----
  uint4* wp = (uint4*)(ws + O_WP);
  auto PK = [&](const float* Wsrc, int off_u4, int N, int K) {
    hipLaunchKernelGGL(pack_kernel, dim3((N*(K/8)+255)/256), dim3(256), 0, stream,
                       Wsrc, wp + off_u4, N, K);
  };
  for (int l = 0; l < LL; ++l) {
    PK(saqkvw + (size_t)l*110592, l*PL4 + OFF4_QKV, 576, 192);
    PK(saoutw + (size_t)l*36864,  l*PL4 + OFF4_SAO, 192, 192);
    PK(caqkvw + (size_t)l*110592, l*PL4 + OFF4_CAQ, 192, 192);  // first 192 rows = Wq
    PK(caoutw + (size_t)l*36864,  l*PL4 + OFF4_CAO, 192, 192);
    PK(ff1w   + (size_t)l*98304,  l*PL4 + OFF4_FF1, 512, 192);
    PK(ff2w   + (size_t)l*98304,  l*PL4 + OFF4_FF2, 192, 512);
  }
  PK(h1w, OFF4_H1, 192, 192);
  PK(h2w, OFF4_H2, 256, 192);

  hipLaunchKernelGGL(pe_kernel, dim3((SM*DM+255)/256), dim3(256), 0, stream, ws+O_PE);

  // ---- CA K/V hoisted: KV[l] = mem @ [Wk;Wv]^T + [bk;bv] (bf16; overlaps dead xp1/h) ----
  __hip_bfloat16* kvb = (__hip_bfloat16*)ws;
  for (int l = 0; l < LL; ++l) {
    hipLaunchKernelGGL((gemm_nt<true,true>), dim3(384/64, NNODES/64), dim3(256), 0, stream,
                       ws+O_MEM, caqkvw + (size_t)l*110592 + (size_t)192*192,
                       caqkvb + l*576 + 192, (float*)nullptr,
                       kvb + (size_t)l*NNODES*384, NNODES, 384, DM);
  }

  hipLaunchKernelGGL(decode_kernel, dim3(BZ), dim3(512), 0, stream,
                     ws+O_MEM, (const u16*)kvb, wp, ws+O_PE, (u32*)(ws+O_VSA), tgt_idx,
                     saqkvb, saoutb, caqkvb, caoutb, ff1b, ff2b, lng, lnb, h1b, h2b,
                     out, adj);
}

// Round 4
// 7966.528 us; speedup vs baseline: 1.4206x; 1.0590x over previous
//
#include <hip/hip_runtime.h>
#include <hip/hip_bf16.h>
#include <math.h>

#define DEV __device__ __forceinline__
typedef unsigned int u32;
typedef unsigned short u16;

constexpr int NNODES = 16384;
constexpr int NEDGE  = 262144;
constexpr int NEL    = NEDGE + NNODES;
constexpr int FIN    = 256;
constexpr int C1     = 384;
constexpr int DM     = 192;
constexpr int BZ     = 128;
constexpr int NPG_   = 128;
constexpr int LL     = 4;
constexpr int PP     = 32;
constexpr int SM     = 33;
constexpr int DFF_   = 512;

// packed-weight layout (uint4 units, [K/8][N]) per layer
constexpr int PL4     = 52224;
constexpr int OFF4_QKV = 0;        // 576x192 -> 24*576
constexpr int OFF4_SAO = 13824;    // 192x192 -> 24*192
constexpr int OFF4_CAQ = 18432;
constexpr int OFF4_CAO = 23040;
constexpr int OFF4_FF1 = 27648;    // 512x192 -> 24*512
constexpr int OFF4_FF2 = 39936;    // 192x512 -> 64*192
constexpr int OFF4_H1  = 4*PL4;           // 208896
constexpr int OFF4_H2  = OFF4_H1 + 4608;  // 213504 ; +6144 -> 219648 u4 total

// ---- workspace layout (float units) ----
constexpr size_t O_XP1 = 0;                       // later overlapped by bf16 CA-KV
constexpr size_t O_H   = 6291456;
constexpr size_t O_XP2 = 12582912;
constexpr size_t O_MEM = 15728640;
constexpr size_t O_VSAT= 18874368;                // SA V cache transposed u16: 128*4*192*34 = 3,342,336 u16
constexpr size_t O_WP  = 20545536;                // packed weights: 219648 u4 = 878592 floats
constexpr size_t O_PE  = 21424128;
constexpr size_t O_AL1S= O_PE + 6336;
constexpr size_t O_AL1D= O_AL1S + 65536;
constexpr size_t O_AL2S= O_AL1D + 65536;
constexpr size_t O_AL2D= O_AL2S + 16384;
constexpr size_t O_CNT = O_AL2D + 16384;
constexpr size_t O_BASE= O_CNT + 16384;
constexpr size_t O_FILL= O_BASE + 16384;
constexpr size_t O_CSRC= O_FILL + 16384;

DEV float gelu_f(float v) { return 0.5f*v*(1.0f + erff(v*0.7071067811865475f)); }
DEV float bflo(u32 w) { return __uint_as_float(w << 16); }
DEV float bfhi(u32 w) { return __uint_as_float(w & 0xffff0000u); }
DEV float bfu(u16 u)  { return __uint_as_float(((u32)u) << 16); }
DEV u16 bf16u(float a) {
  __hip_bfloat16 h = __float2bfloat16(a);
  return *reinterpret_cast<u16*>(&h);
}
DEV u32 pk2(float a, float b) {
  return (u32)bf16u(a) | ((u32)bf16u(b) << 16);
}
DEV void fma8(float& a, uint4 w, float4 xa, float4 xb) {
  a = fmaf(bflo(w.x), xa.x, a); a = fmaf(bfhi(w.x), xa.y, a);
  a = fmaf(bflo(w.y), xa.z, a); a = fmaf(bfhi(w.y), xa.w, a);
  a = fmaf(bflo(w.z), xb.x, a); a = fmaf(bfhi(w.z), xb.y, a);
  a = fmaf(bflo(w.w), xb.z, a); a = fmaf(bfhi(w.w), xb.w, a);
}
// dot of one weight column (NU4 u4 rows, row stride STRIDE u4) with xv; 4 accumulators
template<int NU4, int STRIDE>
DEV float dotcol(const uint4* __restrict__ col, const float* __restrict__ xv) {
  const float4* x4 = (const float4*)xv;
  float a0 = 0, a1 = 0, a2 = 0, a3 = 0;
  #pragma unroll
  for (int q = 0; q < NU4; q += 4) {
    uint4 w0 = col[(q+0)*STRIDE];
    uint4 w1 = col[(q+1)*STRIDE];
    uint4 w2 = col[(q+2)*STRIDE];
    uint4 w3 = col[(q+3)*STRIDE];
    fma8(a0, w0, x4[2*q+0], x4[2*q+1]);
    fma8(a1, w1, x4[2*q+2], x4[2*q+3]);
    fma8(a2, w2, x4[2*q+4], x4[2*q+5]);
    fma8(a3, w3, x4[2*q+6], x4[2*q+7]);
  }
  return (a0+a1)+(a2+a3);
}

// ---------------- misc ----------------
__global__ void zero_kernel(float* adj, int* cnt, int* fill) {
  int i = blockIdx.x*256 + threadIdx.x;
  if (i < BZ*SM*SM) adj[i] = 0.f;
  if (i < NNODES) { cnt[i] = 0; fill[i] = 0; }
}

__global__ void pe_kernel(float* pe) {
  int idx = blockIdx.x*256 + threadIdx.x;
  if (idx >= SM*DM) return;
  int p = idx / DM, d = idx % DM;
  int i2 = d >> 1;
  float div = __expf((float)(2*i2) * (-9.210340371976184f / (float)DM));
  float a = (float)p * div;
  pe[idx] = (d & 1) ? cosf(a) : sinf(a);
}

// pack W[N][K] fp32 -> P[kq*N+o] = 8 bf16 of W[o][8kq..8kq+7]
__global__ void pack_kernel(const float* __restrict__ W, uint4* __restrict__ P, int N, int K) {
  int idx = blockIdx.x*256 + threadIdx.x;
  if (idx >= N*(K>>3)) return;
  int o = idx % N, kq = idx / N;
  const float* r = W + (size_t)o*K + 8*kq;
  uint4 u;
  u.x = pk2(r[0], r[1]); u.y = pk2(r[2], r[3]);
  u.z = pk2(r[4], r[5]); u.w = pk2(r[6], r[7]);
  P[idx] = u;
}

// ---------------- generic fp32 GEMM: C[M,N] = A[M,K] @ W[N,K]^T (+bias) ----------------
template<bool BIAS, bool BF16OUT>
__global__ __launch_bounds__(256) void gemm_nt(const float* __restrict__ A,
    const float* __restrict__ W, const float* __restrict__ bias,
    float* __restrict__ Cf, __hip_bfloat16* __restrict__ Cb, int M, int N, int K)
{
  __shared__ float As[16][68];
  __shared__ float Ws[16][68];
  const int bm = blockIdx.y*64, bn = blockIdx.x*64;
  const int t = threadIdx.x, tx = t & 15, ty = t >> 4;
  float acc[4][4] = {};
  for (int k0 = 0; k0 < K; k0 += 16) {
    #pragma unroll
    for (int i = 0; i < 4; ++i) {
      int idx = t + i*256, kk = idx & 15, m = idx >> 4;
      As[kk][m] = A[(size_t)(bm+m)*K + k0+kk];
      Ws[kk][m] = W[(size_t)(bn+m)*K + k0+kk];
    }
    __syncthreads();
    #pragma unroll
    for (int kk = 0; kk < 16; ++kk) {
      const float4 a4 = *(const float4*)&As[kk][ty*4];
      const float4 b4 = *(const float4*)&Ws[kk][tx*4];
      const float av[4] = {a4.x,a4.y,a4.z,a4.w};
      const float bv[4] = {b4.x,b4.y,b4.z,b4.w};
      #pragma unroll
      for (int i = 0; i < 4; ++i)
        #pragma unroll
        for (int j = 0; j < 4; ++j)
          acc[i][j] = fmaf(av[i], bv[j], acc[i][j]);
    }
    __syncthreads();
  }
  #pragma unroll
  for (int i = 0; i < 4; ++i) {
    const int m = bm + ty*4 + i;
    #pragma unroll
    for (int j = 0; j < 4; ++j) {
      const int n = bn + tx*4 + j;
      float v = acc[i][j];
      if (BIAS) v += bias[n];
      if (BF16OUT) Cb[(size_t)m*N + n] = __float2bfloat16(v);
      else         Cf[(size_t)m*N + n] = v;
    }
  }
}

// ---------------- GAT helpers ----------------
template<int HEADS, int CH>
__global__ void al_kernel(const float* __restrict__ xp, const float* __restrict__ asrc,
                          const float* __restrict__ adst, float* als, float* ald) {
  int idx = blockIdx.x*256 + threadIdx.x;
  if (idx >= NNODES*HEADS) return;
  int n = idx / HEADS, h = idx % HEADS;
  const float* row = xp + (size_t)n*(HEADS*CH) + h*CH;
  float s = 0, d = 0;
  for (int c = 0; c < CH; ++c) { float v = row[c]; s = fmaf(v, asrc[h*CH+c], s); d = fmaf(v, adst[h*CH+c], d); }
  als[idx] = s; ald[idx] = d;
}

__global__ void count_kernel(const int* __restrict__ dst, int* cnt) {
  int e = blockIdx.x*256 + threadIdx.x;
  if (e < NEDGE) atomicAdd(&cnt[dst[e]], 1);
}

__global__ __launch_bounds__(1024) void scan_kernel(const int* __restrict__ cnt, int* base) {
  __shared__ int tot[1024];
  int t = threadIdx.x;
  int local[16]; int s = 0;
  #pragma unroll
  for (int i = 0; i < 16; ++i) { int v = cnt[t*16+i] + 1; local[i] = s; s += v; }
  tot[t] = s; __syncthreads();
  if (t == 0) { int r = 0; for (int i = 0; i < 1024; ++i) { int v = tot[i]; tot[i] = r; r += v; } }
  __syncthreads();
  int off = tot[t];
  #pragma unroll
  for (int i = 0; i < 16; ++i) base[t*16+i] = off + local[i];
}

__global__ void scatter_kernel(const int* __restrict__ src, const int* __restrict__ dst,
                               const int* __restrict__ base, int* fill, int* csrc) {
  int e = blockIdx.x*256 + threadIdx.x;
  if (e < NEDGE) {
    int d = dst[e];
    int p = atomicAdd(&fill[d], 1);
    csrc[base[d] + p] = src[e];
  } else if (e < NEL) {
    int n = e - NEDGE;
    int p = atomicAdd(&fill[n], 1);
    csrc[base[n] + p] = n;
  }
}

template<int HEADS, int CH, bool ELU>
__global__ __launch_bounds__(128) void agg_kernel(const float* __restrict__ xp,
    const float* __restrict__ als, const float* __restrict__ ald,
    const int* __restrict__ cnt, const int* __restrict__ base, const int* __restrict__ csrc,
    const float* __restrict__ bias, float* __restrict__ out)
{
  constexpr int CO = HEADS*CH;
  constexpr int MAXD = 128;
  int n = blockIdx.x, t = threadIdx.x;
  int deg = cnt[n] + 1, st = base[n];
  if (deg > MAXD) deg = MAXD;
  __shared__ int   srcs[MAXD];
  __shared__ float ex[MAXD][HEADS];
  __shared__ float den[HEADS];
  for (int j = t; j < deg; j += 128) srcs[j] = csrc[st + j];
  __syncthreads();
  for (int idx = t; idx < deg*HEADS; idx += 128) {
    int j = idx / HEADS, h = idx % HEADS;
    float e = als[srcs[j]*HEADS + h] + ald[n*HEADS + h];
    ex[j][h] = (e > 0.f) ? e : 0.2f*e;
  }
  __syncthreads();
  if (t < HEADS) {
    float m = -1e30f;
    for (int j = 0; j < deg; ++j) m = fmaxf(m, ex[j][t]);
    float s = 0;
    for (int j = 0; j < deg; ++j) { float v = __expf(ex[j][t]-m); ex[j][t] = v; s += v; }
    den[t] = 1.0f/(s + 1e-16f);
  }
  __syncthreads();
  for (int c = t; c < CO; c += 128) {
    int h = c / CH;
    float acc = 0;
    for (int j = 0; j < deg; ++j) acc = fmaf(ex[j][h], xp[(size_t)srcs[j]*CO + c], acc);
    float v = acc*den[h] + bias[c];
    if (ELU) v = (v > 0.f) ? v : (__expf(v) - 1.0f);
    out[(size_t)n*CO + c] = v;
  }
}

// ---------------- decode ----------------
__global__ __launch_bounds__(512, 1) void decode_kernel(
    const float* __restrict__ mem, const u16* __restrict__ kvb,
    const uint4* __restrict__ wp, const float* __restrict__ pe,
    u16* __restrict__ vsaT, const int* __restrict__ tgt_idx,
    const float* __restrict__ saqkvb, const float* __restrict__ saoutb,
    const float* __restrict__ caqkvb, const float* __restrict__ caoutb,
    const float* __restrict__ ff1b, const float* __restrict__ ff2b,
    const float* __restrict__ lng, const float* __restrict__ lnb,
    const float* __restrict__ h1b, const float* __restrict__ h2b,
    float* __restrict__ feats, float* __restrict__ adj)
{
  const int b = blockIdx.x, t = threadIdx.x;
  const int wv = t >> 6, lane = t & 63;
  __shared__ u16   ksa16[4*33*194];      // SA K cache, row stride 194 u16 (97 u32) conflict-free
  __shared__ u32   Vlds[128*97];         // CA V slab [node][97]: 96 packed dim-pairs + pad
  __shared__ float lasts[SM][193];
  __shared__ __align__(16) float x[DM];
  __shared__ __align__(16) float qkv[DM];   // q (SA) then CA-q
  __shared__ __align__(16) float attno[DM];
  __shared__ __align__(16) float hid[DFF_];
  __shared__ float prob[33*9 + 7];       // [key][9] odd stride
  __shared__ float cprob[128*9];
  __shared__ float ps[2][DM];
  __shared__ float painv[8], cainv[8], red[16];
  const float scl = 0.2041241452319315f; // 1/sqrt(24)
  const float* tgt0 = mem + ((size_t)b*NPG_ + tgt_idx[b])*DM;
  const uint4* kvb4 = (const uint4*)kvb;
  const u32*   kvb2 = (const u32*)kvb;

  // fused residual(+partials)+LayerNorm: x <- LN(x + ps0 + ps1)
  auto ln_ps = [&](const float* g, const float* be) {
    float v = 0.f;
    if (t < DM) v = x[t] + ps[0][t] + ps[1][t];
    float s = v, q = v*v;
    #pragma unroll
    for (int o = 32; o; o >>= 1) { s += __shfl_down(s, o, 64); q += __shfl_down(q, o, 64); }
    if (lane == 0) { red[wv] = s; red[8+wv] = q; }
    __syncthreads();
    float S = 0, Q = 0;
    #pragma unroll
    for (int w = 0; w < 8; ++w) { S += red[w]; Q += red[8+w]; }
    float mu = S*(1.f/DM), var = Q*(1.f/DM) - mu*mu;
    float rstd = rsqrtf(var + 1e-5f);
    if (t < DM) x[t] = (v-mu)*rstd*g[t] + be[t];
    __syncthreads();
  };
  // split-K2 GEMV N=192 K=192 -> ps
  auto skgemv2 = [&](const uint4* P, const float* bias, const float* xv) {
    if (t < 384) {
      int ks = t >= 192, o = t - 192*ks;
      float a = dotcol<12,192>(P + ks*12*192 + o, xv + 96*ks);
      ps[ks][o] = a + (ks ? 0.f : bias[o]);
    }
  };

  for (int i = 0; i < PP; ++i) {
    if (t < DM) x[t] = ((i == 0) ? tgt0[t] : lasts[i-1][t]) + pe[i*DM + t];
    __syncthreads();
    for (int l = 0; l < LL; ++l) {
      const uint4* WL = wp + (size_t)l*PL4;
      // --- SA qkv: 576 cols K=192; K/V cache stored directly by producing thread ---
      for (int o = t; o < 576; o += 512) {
        float a = saqkvb[l*576 + o] + dotcol<24,576>(WL + OFF4_QKV + o, x);
        if (o < 192)      qkv[o] = a;
        else if (o < 384) ksa16[(l*33 + i)*194 + (o-192)] = bf16u(a);
        else              vsaT[((size_t)(b*4+l)*192 + (o-384))*34 + i] = bf16u(a);
      }
      __syncthreads();
      // --- stage CA V slab -> LDS [node][97] u32 (coalesced, conflict-free reads) ---
      for (int idx = t; idx < 128*96; idx += 512) {
        int node = idx / 96, c = idx - node*96;
        Vlds[node*97 + c] = kvb2[((size_t)l*NNODES + b*NPG_ + node)*192 + 96 + c];
      }
      // --- SA QK^T + softmax (wave = head, lane = key) ---
      {
        float s = -1e30f;
        if (lane <= i) {
          const u32* kr = (const u32*)ksa16 + (l*33 + lane)*97 + wv*12;
          float a0 = 0, a1 = 0;
          #pragma unroll
          for (int c = 0; c < 12; c += 2) {
            u32 w0 = kr[c], w1 = kr[c+1];
            a0 = fmaf(bflo(w0), qkv[wv*24 + 2*c],   a0);
            a0 = fmaf(bfhi(w0), qkv[wv*24 + 2*c+1], a0);
            a1 = fmaf(bflo(w1), qkv[wv*24 + 2*c+2], a1);
            a1 = fmaf(bfhi(w1), qkv[wv*24 + 2*c+3], a1);
          }
          s = (a0+a1) * scl;
        }
        float m = s;
        #pragma unroll
        for (int o2 = 32; o2; o2 >>= 1) m = fmaxf(m, __shfl_xor(m, o2, 64));
        float e = (lane <= i) ? __expf(s - m) : 0.f;
        float sm = e;
        #pragma unroll
        for (int o2 = 32; o2; o2 >>= 1) sm += __shfl_xor(sm, o2, 64);
        if (lane <= i) prob[lane*9 + wv] = e;
        if (lane == 0) painv[wv] = 1.0f / sm;
      }
      __syncthreads();
      // --- SA PV: thread=dim streams its own contiguous vsaT row ---
      if (t < DM) {
        int hh = t / 24;
        const u16* vr = vsaT + ((size_t)(b*4+l)*192 + t)*34;
        float a0 = 0, a1 = 0;
        for (int j = 0; j + 1 <= i; j += 2) {
          a0 = fmaf(prob[j*9 + hh],     bfu(vr[j]),   a0);
          a1 = fmaf(prob[(j+1)*9 + hh], bfu(vr[j+1]), a1);
        }
        if (!(i & 1)) a0 = fmaf(prob[i*9 + hh], bfu(vr[i]), a0);
        attno[t] = (a0 + a1) * painv[hh];
      }
      __syncthreads();
      // --- SA out + residual + LN ---
      skgemv2(WL + OFF4_SAO, saoutb + l*DM, attno);
      __syncthreads();
      ln_ps(lng + (l*3+0)*DM, lnb + (l*3+0)*DM);
      // --- CA q ---
      skgemv2(WL + OFF4_CAQ, caqkvb + l*3*DM, x);
      __syncthreads();
      if (t < DM) qkv[t] = ps[0][t] + ps[1][t];
      __syncthreads();
      // --- CA QK^T: 1024 (key,head) scores over 512 threads ---
      for (int s2 = t; s2 < 1024; s2 += 512) {
        int j = s2 >> 3, hh = s2 & 7;
        const uint4* kr = kvb4 + ((size_t)l*NNODES + b*NPG_ + j)*48 + hh*3;
        uint4 w0 = kr[0], w1 = kr[1], w2 = kr[2];
        const float4* q4 = (const float4*)qkv + hh*6;
        float a0 = 0, a1 = 0, a2 = 0;
        fma8(a0, w0, q4[0], q4[1]);
        fma8(a1, w1, q4[2], q4[3]);
        fma8(a2, w2, q4[4], q4[5]);
        cprob[j*9 + hh] = (a0+a1+a2) * scl;
      }
      __syncthreads();
      // --- CA softmax over 128 keys (wave = head) ---
      {
        float s0 = cprob[lane*9 + wv], s1 = cprob[(lane+64)*9 + wv];
        float m = fmaxf(s0, s1);
        #pragma unroll
        for (int o2 = 32; o2; o2 >>= 1) m = fmaxf(m, __shfl_xor(m, o2, 64));
        float e0 = __expf(s0-m), e1 = __expf(s1-m);
        float sm = e0+e1;
        #pragma unroll
        for (int o2 = 32; o2; o2 >>= 1) sm += __shfl_xor(sm, o2, 64);
        cprob[lane*9 + wv] = e0; cprob[(lane+64)*9 + wv] = e1;
        if (lane == 0) cainv[wv] = 1.0f / sm;
      }
      __syncthreads();
      // --- CA PV from LDS V slab: lanes read 32 consecutive words (paired broadcast) ---
      if (t < 384) {
        int half = t / 192, tm = t - 192*half, hh = tm / 24;
        int w = tm >> 1;
        bool hi = tm & 1;
        int jb = half*64;
        float a0 = 0, a1 = 0;
        #pragma unroll
        for (int j = 0; j < 64; j += 2) {
          u32 v0 = Vlds[(jb+j)*97 + w], v1 = Vlds[(jb+j+1)*97 + w];
          a0 = fmaf(cprob[(jb+j)*9 + hh],   hi ? bfhi(v0) : bflo(v0), a0);
          a1 = fmaf(cprob[(jb+j+1)*9 + hh], hi ? bfhi(v1) : bflo(v1), a1);
        }
        ps[half][tm] = a0 + a1;
      }
      __syncthreads();
      if (t < DM) attno[t] = (ps[0][t] + ps[1][t]) * cainv[t/24];
      __syncthreads();
      // --- CA out + residual + LN ---
      skgemv2(WL + OFF4_CAO, caoutb + l*DM, attno);
      __syncthreads();
      ln_ps(lng + (l*3+1)*DM, lnb + (l*3+1)*DM);
      // --- FF1: 512 cols K=192 ---
      hid[t] = gelu_f(ff1b[l*DFF_ + t] + dotcol<24,512>(WL + OFF4_FF1 + t, x));
      __syncthreads();
      // --- FF2: 192 cols K=512 split-K2 ---
      if (t < 384) {
        int ks = t >= 192, o = t - 192*ks;
        float a = dotcol<32,192>(WL + OFF4_FF2 + ks*32*192 + o, hid + 256*ks);
        ps[ks][o] = a + (ks ? 0.f : ff2b[l*DM + o]);
      }
      __syncthreads();
      ln_ps(lng + (l*3+2)*DM, lnb + (l*3+2)*DM);
    }
    // --- head: h1(gelu) -> h2 -> feats ; lasts ; adjacency ---
    skgemv2(wp + OFF4_H1, h1b, x);
    __syncthreads();
    if (t < DM) { hid[t] = gelu_f(ps[0][t] + ps[1][t]); lasts[i][t] = x[t]; }
    __syncthreads();
    if (t < 256)
      feats[((size_t)b*PP + i)*256 + t] = h2b[t] + dotcol<24,256>(wp + OFF4_H2 + t, hid);
    if (t <= i) {
      float a = 0.f;
      for (int d = 0; d < DM; ++d) a = fmaf(lasts[t][d], lasts[i][d], a);
      if (t == 0) {
        adj[((size_t)b*SM + i)*SM + 32] = a;
        adj[((size_t)b*SM + 32)*SM + i] = a;
      } else {
        int j2 = t - 1;
        adj[((size_t)b*SM + j2)*SM + i] = a;
        adj[((size_t)b*SM + i)*SM + j2] = a;
      }
    }
    __syncthreads();
  }
}

// ---------------- launch ----------------
extern "C" void kernel_launch(void* const* d_in, const int* in_sizes, int n_in,
                              void* d_out, int out_size, void* d_ws, size_t ws_size,
                              hipStream_t stream) {
  (void)in_sizes; (void)n_in; (void)out_size; (void)ws_size;
  const float* x_in    = (const float*)d_in[0];
  const int*   ei      = (const int*)d_in[1];
  const int*   tgt_idx = (const int*)d_in[2];
  const float* gat1_w  = (const float*)d_in[5];
  const float* g1as    = (const float*)d_in[6];
  const float* g1ad    = (const float*)d_in[7];
  const float* g1b     = (const float*)d_in[8];
  const float* gat2_w  = (const float*)d_in[9];
  const float* g2as    = (const float*)d_in[10];
  const float* g2ad    = (const float*)d_in[11];
  const float* g2b     = (const float*)d_in[12];
  const float* saqkvw  = (const float*)d_in[13];
  const float* saqkvb  = (const float*)d_in[14];
  const float* saoutw  = (const float*)d_in[15];
  const float* saoutb  = (const float*)d_in[16];
  const float* caqkvw  = (const float*)d_in[17];
  const float* caqkvb  = (const float*)d_in[18];
  const float* caoutw  = (const float*)d_in[19];
  const float* caoutb  = (const float*)d_in[20];
  const float* ff1w    = (const float*)d_in[21];
  const float* ff1b    = (const float*)d_in[22];
  const float* ff2w    = (const float*)d_in[23];
  const float* ff2b    = (const float*)d_in[24];
  const float* lng     = (const float*)d_in[25];
  const float* lnb     = (const float*)d_in[26];
  const float* h1w     = (const float*)d_in[27];
  const float* h1b     = (const float*)d_in[28];
  const float* h2w     = (const float*)d_in[29];
  const float* h2b     = (const float*)d_in[30];

  float* ws  = (float*)d_ws;
  float* out = (float*)d_out;
  float* adj = out + (size_t)BZ*PP*256;

  const int* src = ei;
  const int* dst = ei + NEDGE;

  int* cnt  = (int*)(ws + O_CNT);
  int* base = (int*)(ws + O_BASE);
  int* fill = (int*)(ws + O_FILL);
  int* csrc = (int*)(ws + O_CSRC);

  hipLaunchKernelGGL(zero_kernel, dim3(545), dim3(256), 0, stream, adj, cnt, fill);

  // ---- GAT1 ----
  hipLaunchKernelGGL((gemm_nt<false,false>), dim3(C1/64, NNODES/64), dim3(256), 0, stream,
                     x_in, gat1_w, (const float*)nullptr, ws + O_XP1, (__hip_bfloat16*)nullptr,
                     NNODES, C1, FIN);
  hipLaunchKernelGGL((al_kernel<4,96>), dim3(NNODES*4/256), dim3(256), 0, stream,
                     ws+O_XP1, g1as, g1ad, ws+O_AL1S, ws+O_AL1D);
  hipLaunchKernelGGL(count_kernel, dim3(NEDGE/256), dim3(256), 0, stream, dst, cnt);
  hipLaunchKernelGGL(scan_kernel, dim3(1), dim3(1024), 0, stream, cnt, base);
  hipLaunchKernelGGL(scatter_kernel, dim3(NEL/256), dim3(256), 0, stream, src, dst, base, fill, csrc);
  hipLaunchKernelGGL((agg_kernel<4,96,true>), dim3(NNODES), dim3(128), 0, stream,
                     ws+O_XP1, ws+O_AL1S, ws+O_AL1D, cnt, base, csrc, g1b, ws+O_H);

  // ---- GAT2 ----
  hipLaunchKernelGGL((gemm_nt<false,false>), dim3(DM/64, NNODES/64), dim3(256), 0, stream,
                     ws+O_H, gat2_w, (const float*)nullptr, ws+O_XP2, (__hip_bfloat16*)nullptr,
                     NNODES, DM, C1);
  hipLaunchKernelGGL((al_kernel<1,192>), dim3(NNODES/256), dim3(256), 0, stream,
                     ws+O_XP2, g2as, g2ad, ws+O_AL2S, ws+O_AL2D);
  hipLaunchKernelGGL((agg_kernel<1,192,false>), dim3(NNODES), dim3(128), 0, stream,
                     ws+O_XP2, ws+O_AL2S, ws+O_AL2D, cnt, base, csrc, g2b, ws+O_MEM);

  // ---- pack decode weights to bf16 [K/8][N] uint4 ----
  uint4* wp = (uint4*)(ws + O_WP);
  auto PK = [&](const float* Wsrc, int off_u4, int N, int K) {
    hipLaunchKernelGGL(pack_kernel, dim3((N*(K/8)+255)/256), dim3(256), 0, stream,
                       Wsrc, wp + off_u4, N, K);
  };
  for (int l = 0; l < LL; ++l) {
    PK(saqkvw + (size_t)l*110592, l*PL4 + OFF4_QKV, 576, 192);
    PK(saoutw + (size_t)l*36864,  l*PL4 + OFF4_SAO, 192, 192);
    PK(caqkvw + (size_t)l*110592, l*PL4 + OFF4_CAQ, 192, 192);  // first 192 rows = Wq
    PK(caoutw + (size_t)l*36864,  l*PL4 + OFF4_CAO, 192, 192);
    PK(ff1w   + (size_t)l*98304,  l*PL4 + OFF4_FF1, 512, 192);
    PK(ff2w   + (size_t)l*98304,  l*PL4 + OFF4_FF2, 192, 512);
  }
  PK(h1w, OFF4_H1, 192, 192);
  PK(h2w, OFF4_H2, 256, 192);

  hipLaunchKernelGGL(pe_kernel, dim3((SM*DM+255)/256), dim3(256), 0, stream, ws+O_PE);

  // ---- CA K/V hoisted: KV[l] = mem @ [Wk;Wv]^T + [bk;bv] (bf16; overlaps dead xp1/h) ----
  __hip_bfloat16* kvb = (__hip_bfloat16*)ws;
  for (int l = 0; l < LL; ++l) {
    hipLaunchKernelGGL((gemm_nt<true,true>), dim3(384/64, NNODES/64), dim3(256), 0, stream,
                       ws+O_MEM, caqkvw + (size_t)l*110592 + (size_t)192*192,
                       caqkvb + l*576 + 192, (float*)nullptr,
                       kvb + (size_t)l*NNODES*384, NNODES, 384, DM);
  }

  hipLaunchKernelGGL(decode_kernel, dim3(BZ), dim3(512), 0, stream,
                     ws+O_MEM, (const u16*)kvb, wp, ws+O_PE, (u16*)(ws+O_VSAT), tgt_idx,
                     saqkvb, saoutb, caqkvb, caoutb, ff1b, ff2b, lng, lnb, h1b, h2b,
                     out, adj);
}

// Round 5
// 4499.046 us; speedup vs baseline: 2.5154x; 1.7707x over previous
//
#include <hip/hip_runtime.h>
#include <hip/hip_bf16.h>
#include <math.h>

#define DEV __device__ __forceinline__
typedef unsigned int u32;
typedef unsigned short u16;

constexpr int NNODES = 16384;
constexpr int NEDGE  = 262144;
constexpr int NEL    = NEDGE + NNODES;
constexpr int FIN    = 256;
constexpr int C1     = 384;
constexpr int DM     = 192;
constexpr int BZ     = 128;
constexpr int NPG_   = 128;
constexpr int LL     = 4;
constexpr int PP     = 32;
constexpr int SM     = 33;
constexpr int DFF_   = 512;

// packed-weight layout (uint4 units, [K/8][N]) per layer
constexpr int PL4     = 52224;
constexpr int OFF4_QKV = 0;        // 576x192 -> 24*576
constexpr int OFF4_SAO = 13824;    // 192x192 -> 24*192
constexpr int OFF4_CAQ = 18432;
constexpr int OFF4_CAO = 23040;
constexpr int OFF4_FF1 = 27648;    // 512x192 -> 24*512
constexpr int OFF4_FF2 = 39936;    // 192x512 -> 64*192
constexpr int OFF4_H1  = 4*PL4;           // 208896
constexpr int OFF4_H2  = OFF4_H1 + 4608;  // 213504 ; +6144 -> 219648 u4 total

// ---- workspace layout (float units) ----
// kvk (CA K bf16 [l][node][192])   : ws[0 .. 6291456)          (overlaps dead XP1)
// vT  (CA V bf16 [l][dim][node16k]): ws[6291456 .. 12582912)   (overlaps dead H)
constexpr size_t O_KVK = 0;
constexpr size_t O_VT  = 6291456;
constexpr size_t O_XP1 = 0;
constexpr size_t O_H   = 6291456;
constexpr size_t O_XP2 = 12582912;
constexpr size_t O_MEM = 15728640;
constexpr size_t O_VSAT= 18874368;                // SA V cache transposed u16: 128*4*192*34
constexpr size_t O_WP  = 20545536;                // packed weights: 219648 u4 = 878592 floats
constexpr size_t O_PE  = 21424128;
constexpr size_t O_AL1S= O_PE + 6336;
constexpr size_t O_AL1D= O_AL1S + 65536;
constexpr size_t O_AL2S= O_AL1D + 65536;
constexpr size_t O_AL2D= O_AL2S + 16384;
constexpr size_t O_CNT = O_AL2D + 16384;
constexpr size_t O_BASE= O_CNT + 16384;
constexpr size_t O_FILL= O_BASE + 16384;
constexpr size_t O_CSRC= O_FILL + 16384;

DEV float gelu_f(float v) { return 0.5f*v*(1.0f + erff(v*0.7071067811865475f)); }
DEV float bflo(u32 w) { return __uint_as_float(w << 16); }
DEV float bfhi(u32 w) { return __uint_as_float(w & 0xffff0000u); }
DEV float bfu(u16 u)  { return __uint_as_float(((u32)u) << 16); }
DEV u16 bf16u(float a) {
  __hip_bfloat16 h = __float2bfloat16(a);
  return *reinterpret_cast<u16*>(&h);
}
DEV u32 pk2(float a, float b) {
  return (u32)bf16u(a) | ((u32)bf16u(b) << 16);
}
DEV void fma8(float& a, uint4 w, float4 xa, float4 xb) {
  a = fmaf(bflo(w.x), xa.x, a); a = fmaf(bfhi(w.x), xa.y, a);
  a = fmaf(bflo(w.y), xa.z, a); a = fmaf(bfhi(w.y), xa.w, a);
  a = fmaf(bflo(w.z), xb.x, a); a = fmaf(bfhi(w.z), xb.y, a);
  a = fmaf(bflo(w.w), xb.z, a); a = fmaf(bfhi(w.w), xb.w, a);
}
// dot of one weight column (NU4 u4 rows at row-stride STRIDE u4) with xv; 4 round-robin accs
template<int NU4, int STRIDE>
DEV float dotcol(const uint4* __restrict__ col, const float* __restrict__ xv) {
  const float4* x4 = (const float4*)xv;
  float a0 = 0, a1 = 0, a2 = 0, a3 = 0;
  #pragma unroll
  for (int q = 0; q < NU4; ++q) {
    uint4 w = col[(size_t)q*STRIDE];
    if ((q & 3) == 0) fma8(a0, w, x4[2*q], x4[2*q+1]);
    else if ((q & 3) == 1) fma8(a1, w, x4[2*q], x4[2*q+1]);
    else if ((q & 3) == 2) fma8(a2, w, x4[2*q], x4[2*q+1]);
    else fma8(a3, w, x4[2*q], x4[2*q+1]);
  }
  return (a0+a1)+(a2+a3);
}

// ---------------- misc ----------------
__global__ void zero_kernel(float* adj, int* cnt, int* fill) {
  int i = blockIdx.x*256 + threadIdx.x;
  if (i < BZ*SM*SM) adj[i] = 0.f;
  if (i < NNODES) { cnt[i] = 0; fill[i] = 0; }
}

__global__ void pe_kernel(float* pe) {
  int idx = blockIdx.x*256 + threadIdx.x;
  if (idx >= SM*DM) return;
  int p = idx / DM, d = idx % DM;
  int i2 = d >> 1;
  float div = __expf((float)(2*i2) * (-9.210340371976184f / (float)DM));
  float a = (float)p * div;
  pe[idx] = (d & 1) ? cosf(a) : sinf(a);
}

// pack W[N][K] fp32 -> P[kq*N+o] = 8 bf16 of W[o][8kq..8kq+7]
__global__ void pack_kernel(const float* __restrict__ W, uint4* __restrict__ P, int N, int K) {
  int idx = blockIdx.x*256 + threadIdx.x;
  if (idx >= N*(K>>3)) return;
  int o = idx % N, kq = idx / N;
  const float* r = W + (size_t)o*K + 8*kq;
  uint4 u;
  u.x = pk2(r[0], r[1]); u.y = pk2(r[2], r[3]);
  u.z = pk2(r[4], r[5]); u.w = pk2(r[6], r[7]);
  P[idx] = u;
}

// ---------------- generic fp32 GEMM: C[M,N] = A[M,K] @ W[N,K]^T (+bias) ----------------
// BMODE: 0 none, 1 column bias (bias[n]), 2 row bias (bias[m])
template<int BMODE, bool BF16OUT>
__global__ __launch_bounds__(256) void gemm_nt(const float* __restrict__ A,
    const float* __restrict__ W, const float* __restrict__ bias,
    float* __restrict__ Cf, __hip_bfloat16* __restrict__ Cb, int M, int N, int K)
{
  __shared__ float As[16][68];
  __shared__ float Ws[16][68];
  const int bm = blockIdx.y*64, bn = blockIdx.x*64;
  const int t = threadIdx.x, tx = t & 15, ty = t >> 4;
  float acc[4][4] = {};
  for (int k0 = 0; k0 < K; k0 += 16) {
    #pragma unroll
    for (int i = 0; i < 4; ++i) {
      int idx = t + i*256, kk = idx & 15, m = idx >> 4;
      As[kk][m] = A[(size_t)(bm+m)*K + k0+kk];
      Ws[kk][m] = W[(size_t)(bn+m)*K + k0+kk];
    }
    __syncthreads();
    #pragma unroll
    for (int kk = 0; kk < 16; ++kk) {
      const float4 a4 = *(const float4*)&As[kk][ty*4];
      const float4 b4 = *(const float4*)&Ws[kk][tx*4];
      const float av[4] = {a4.x,a4.y,a4.z,a4.w};
      const float bv[4] = {b4.x,b4.y,b4.z,b4.w};
      #pragma unroll
      for (int i = 0; i < 4; ++i)
        #pragma unroll
        for (int j = 0; j < 4; ++j)
          acc[i][j] = fmaf(av[i], bv[j], acc[i][j]);
    }
    __syncthreads();
  }
  #pragma unroll
  for (int i = 0; i < 4; ++i) {
    const int m = bm + ty*4 + i;
    #pragma unroll
    for (int j = 0; j < 4; ++j) {
      const int n = bn + tx*4 + j;
      float v = acc[i][j];
      if (BMODE == 1) v += bias[n];
      if (BMODE == 2) v += bias[m];
      if (BF16OUT) Cb[(size_t)m*N + n] = __float2bfloat16(v);
      else         Cf[(size_t)m*N + n] = v;
    }
  }
}

// ---------------- GAT helpers ----------------
template<int HEADS, int CH>
__global__ void al_kernel(const float* __restrict__ xp, const float* __restrict__ asrc,
                          const float* __restrict__ adst, float* als, float* ald) {
  int idx = blockIdx.x*256 + threadIdx.x;
  if (idx >= NNODES*HEADS) return;
  int n = idx / HEADS, h = idx % HEADS;
  const float* row = xp + (size_t)n*(HEADS*CH) + h*CH;
  float s = 0, d = 0;
  for (int c = 0; c < CH; ++c) { float v = row[c]; s = fmaf(v, asrc[h*CH+c], s); d = fmaf(v, adst[h*CH+c], d); }
  als[idx] = s; ald[idx] = d;
}

__global__ void count_kernel(const int* __restrict__ dst, int* cnt) {
  int e = blockIdx.x*256 + threadIdx.x;
  if (e < NEDGE) atomicAdd(&cnt[dst[e]], 1);
}

__global__ __launch_bounds__(1024) void scan_kernel(const int* __restrict__ cnt, int* base) {
  __shared__ int tot[1024];
  int t = threadIdx.x;
  int local[16]; int s = 0;
  #pragma unroll
  for (int i = 0; i < 16; ++i) { int v = cnt[t*16+i] + 1; local[i] = s; s += v; }
  tot[t] = s; __syncthreads();
  if (t == 0) { int r = 0; for (int i = 0; i < 1024; ++i) { int v = tot[i]; tot[i] = r; r += v; } }
  __syncthreads();
  int off = tot[t];
  #pragma unroll
  for (int i = 0; i < 16; ++i) base[t*16+i] = off + local[i];
}

__global__ void scatter_kernel(const int* __restrict__ src, const int* __restrict__ dst,
                               const int* __restrict__ base, int* fill, int* csrc) {
  int e = blockIdx.x*256 + threadIdx.x;
  if (e < NEDGE) {
    int d = dst[e];
    int p = atomicAdd(&fill[d], 1);
    csrc[base[d] + p] = src[e];
  } else if (e < NEL) {
    int n = e - NEDGE;
    int p = atomicAdd(&fill[n], 1);
    csrc[base[n] + p] = n;
  }
}

template<int HEADS, int CH, bool ELU>
__global__ __launch_bounds__(128) void agg_kernel(const float* __restrict__ xp,
    const float* __restrict__ als, const float* __restrict__ ald,
    const int* __restrict__ cnt, const int* __restrict__ base, const int* __restrict__ csrc,
    const float* __restrict__ bias, float* __restrict__ out)
{
  constexpr int CO = HEADS*CH;
  constexpr int MAXD = 128;
  int n = blockIdx.x, t = threadIdx.x;
  int deg = cnt[n] + 1, st = base[n];
  if (deg > MAXD) deg = MAXD;
  __shared__ int   srcs[MAXD];
  __shared__ float ex[MAXD][HEADS];
  __shared__ float den[HEADS];
  for (int j = t; j < deg; j += 128) srcs[j] = csrc[st + j];
  __syncthreads();
  for (int idx = t; idx < deg*HEADS; idx += 128) {
    int j = idx / HEADS, h = idx % HEADS;
    float e = als[srcs[j]*HEADS + h] + ald[n*HEADS + h];
    ex[j][h] = (e > 0.f) ? e : 0.2f*e;
  }
  __syncthreads();
  if (t < HEADS) {
    float m = -1e30f;
    for (int j = 0; j < deg; ++j) m = fmaxf(m, ex[j][t]);
    float s = 0;
    for (int j = 0; j < deg; ++j) { float v = __expf(ex[j][t]-m); ex[j][t] = v; s += v; }
    den[t] = 1.0f/(s + 1e-16f);
  }
  __syncthreads();
  for (int c = t; c < CO; c += 128) {
    int h = c / CH;
    float acc = 0;
    for (int j = 0; j < deg; ++j) acc = fmaf(ex[j][h], xp[(size_t)srcs[j]*CO + c], acc);
    float v = acc*den[h] + bias[c];
    if (ELU) v = (v > 0.f) ? v : (__expf(v) - 1.0f);
    out[(size_t)n*CO + c] = v;
  }
}

// ---------------- decode (1024 threads: 16 waves, 4/SIMD) ----------------
__global__ __launch_bounds__(1024, 1) void decode_kernel(
    const float* __restrict__ mem, const u16* __restrict__ kvk, const u16* __restrict__ vT,
    const uint4* __restrict__ wp, const float* __restrict__ pe,
    u16* __restrict__ vsaT, const int* __restrict__ tgt_idx,
    const float* __restrict__ saqkvb, const float* __restrict__ saoutb,
    const float* __restrict__ caqkvb, const float* __restrict__ caoutb,
    const float* __restrict__ ff1b, const float* __restrict__ ff2b,
    const float* __restrict__ lng, const float* __restrict__ lnb,
    const float* __restrict__ h1b, const float* __restrict__ h2b,
    float* __restrict__ feats, float* __restrict__ adj)
{
  const int b = blockIdx.x, t = threadIdx.x;
  const int wv = t >> 6, lane = t & 63;
  __shared__ u16   ksa16[4*33*194];      // SA K cache, row stride 194 u16 (97 u32) conflict-free
  __shared__ float lasts[SM][193];
  __shared__ __align__(16) float x[DM];
  __shared__ __align__(16) float qkv[DM];
  __shared__ __align__(16) float attno[DM];
  __shared__ __align__(16) float hid[DFF_];
  __shared__ float prob[33*9 + 7];
  __shared__ float cprob[128*9 + 2];
  __shared__ __align__(16) float psA[1152];
  __shared__ float painv[8], cainv[8], red[16];
  const float scl = 0.2041241452319315f; // 1/sqrt(24)
  const float* tgt0 = mem + ((size_t)b*NPG_ + tgt_idx[b])*DM;

  // x <- LN(x + psA4) ; psA holds 4 split-K partials
  auto ln_ps4 = [&](const float* g, const float* be) {
    float v = 0.f;
    if (t < DM) v = x[t] + ((psA[t]+psA[192+t]) + (psA[384+t]+psA[576+t]));
    float s = v, q = v*v;
    #pragma unroll
    for (int o = 32; o; o >>= 1) { s += __shfl_down(s, o, 64); q += __shfl_down(q, o, 64); }
    if (lane == 0 && wv < 3) { red[wv] = s; red[8+wv] = q; }
    __syncthreads();
    float S = red[0]+red[1]+red[2];
    float Q = red[8]+red[9]+red[10];
    float mu = S*(1.f/DM), var = Q*(1.f/DM) - mu*mu;
    float rstd = rsqrtf(var + 1e-5f);
    if (t < DM) x[t] = (v-mu)*rstd*g[t] + be[t];
    __syncthreads();
  };
  // split-K4 GEMV N=192 K=192 -> psA[4][192]
  auto skgemv4 = [&](const uint4* P, const float* xv, const float* bias) {
    if (t < 768) {
      int ks = t/192, o = t - ks*192;
      psA[t] = (ks ? 0.f : bias[o]) + dotcol<6,192>(P + ks*6*192 + o, xv + 48*ks);
    }
  };

  for (int i = 0; i < PP; ++i) {
    if (t < DM) x[t] = ((i == 0) ? tgt0[t] : lasts[i-1][t]) + pe[i*DM + t];
    __syncthreads();
    for (int l = 0; l < LL; ++l) {
      const uint4* WL = wp + (size_t)l*PL4;
      // --- SA qkv: 576 cols, split-K2 = 1152 units over 1024 threads ---
      {
        int ks = t/576, o = t - ks*576;
        psA[t] = (ks ? 0.f : saqkvb[l*576+o]) + dotcol<12,576>(WL + OFF4_QKV + ks*12*576 + o, x + 96*ks);
        if (t < 128) {
          int o2 = 448 + t;
          psA[1024 + t] = dotcol<12,576>(WL + OFF4_QKV + 12*576 + o2, x + 96);
        }
      }
      __syncthreads();
      // --- combine + route to q / K-cache(LDS) / V-cache(global transposed) ---
      if (t < 576) {
        float a = psA[t] + psA[576+t];
        if (t < 192)      qkv[t] = a;
        else if (t < 384) ksa16[(l*33 + i)*194 + (t-192)] = bf16u(a);
        else              vsaT[((size_t)(b*4+l)*192 + (t-384))*34 + i] = bf16u(a);
      }
      __syncthreads();
      // --- SA QK^T + softmax (waves 0-7 = heads) ---
      if (wv < 8) {
        float s = -1e30f;
        if (lane <= i) {
          const u32* kr = (const u32*)ksa16 + (l*33 + lane)*97 + wv*12;
          float a0 = 0, a1 = 0;
          #pragma unroll
          for (int c = 0; c < 12; c += 2) {
            u32 w0 = kr[c], w1 = kr[c+1];
            a0 = fmaf(bflo(w0), qkv[wv*24 + 2*c],   a0);
            a0 = fmaf(bfhi(w0), qkv[wv*24 + 2*c+1], a0);
            a1 = fmaf(bflo(w1), qkv[wv*24 + 2*c+2], a1);
            a1 = fmaf(bfhi(w1), qkv[wv*24 + 2*c+3], a1);
          }
          s = (a0+a1) * scl;
        }
        float m = s;
        #pragma unroll
        for (int o2 = 32; o2; o2 >>= 1) m = fmaxf(m, __shfl_xor(m, o2, 64));
        float e = (lane <= i) ? __expf(s - m) : 0.f;
        float sm = e;
        #pragma unroll
        for (int o2 = 32; o2; o2 >>= 1) sm += __shfl_xor(sm, o2, 64);
        if (lane <= i) prob[lane*9 + wv] = e;
        if (lane == 0) painv[wv] = 1.0f / sm;
      }
      __syncthreads();
      // --- SA PV: thread=dim streams its own contiguous vsaT row ---
      if (t < DM) {
        int hh = t / 24;
        const u16* vr = vsaT + ((size_t)(b*4+l)*192 + t)*34;
        float a0 = 0, a1 = 0;
        for (int j = 0; j + 1 <= i; j += 2) {
          a0 = fmaf(prob[j*9 + hh],     bfu(vr[j]),   a0);
          a1 = fmaf(prob[(j+1)*9 + hh], bfu(vr[j+1]), a1);
        }
        if (!(i & 1)) a0 = fmaf(prob[i*9 + hh], bfu(vr[i]), a0);
        attno[t] = (a0 + a1) * painv[hh];
      }
      __syncthreads();
      // --- SA out (split-K4) + residual + LN ---
      skgemv4(WL + OFF4_SAO, attno, saoutb + l*DM);
      __syncthreads();
      ln_ps4(lng + (l*3+0)*DM, lnb + (l*3+0)*DM);
      // --- CA q (split-K4) ---
      skgemv4(WL + OFF4_CAQ, x, caqkvb + l*3*DM);
      __syncthreads();
      if (t < DM) qkv[t] = (psA[t]+psA[192+t]) + (psA[384+t]+psA[576+t]);
      __syncthreads();
      // --- CA QK^T: 1024 (key,head) threads ---
      {
        int j = t >> 3, hh = t & 7;
        const uint4* kr = (const uint4*)kvk + ((size_t)l*NNODES + b*NPG_ + j)*24 + hh*3;
        uint4 w0 = kr[0], w1 = kr[1], w2 = kr[2];
        const float4* q4 = (const float4*)qkv + hh*6;
        float a0 = 0, a1 = 0, a2 = 0;
        fma8(a0, w0, q4[0], q4[1]);
        fma8(a1, w1, q4[2], q4[3]);
        fma8(a2, w2, q4[4], q4[5]);
        cprob[j*9 + hh] = (a0+a1+a2) * scl;
      }
      __syncthreads();
      // --- CA softmax over 128 keys (waves 0-7 = heads) ---
      if (wv < 8) {
        float s0 = cprob[lane*9 + wv], s1 = cprob[(lane+64)*9 + wv];
        float m = fmaxf(s0, s1);
        #pragma unroll
        for (int o2 = 32; o2; o2 >>= 1) m = fmaxf(m, __shfl_xor(m, o2, 64));
        float e0 = __expf(s0-m), e1 = __expf(s1-m);
        float sm = e0+e1;
        #pragma unroll
        for (int o2 = 32; o2; o2 >>= 1) sm += __shfl_xor(sm, o2, 64);
        cprob[lane*9 + wv] = e0; cprob[(lane+64)*9 + wv] = e1;
        if (lane == 0) cainv[wv] = 1.0f / sm;
      }
      __syncthreads();
      // --- CA PV: split-j2, V transposed in global ([dim][node], contiguous 128B rows) ---
      if (t < 384) {
        int half = t/192, tm = t - half*192, hh = tm / 24;
        const uint4* v4 = (const uint4*)(vT + ((size_t)l*DM + tm)*NNODES + b*NPG_ + half*64);
        int jb = half*64;
        float a0 = 0, a1 = 0;
        #pragma unroll
        for (int q = 0; q < 8; ++q) {
          uint4 w = v4[q];
          int j0 = jb + q*8;
          a0 = fmaf(cprob[(j0+0)*9 + hh], bflo(w.x), a0);
          a1 = fmaf(cprob[(j0+1)*9 + hh], bfhi(w.x), a1);
          a0 = fmaf(cprob[(j0+2)*9 + hh], bflo(w.y), a0);
          a1 = fmaf(cprob[(j0+3)*9 + hh], bfhi(w.y), a1);
          a0 = fmaf(cprob[(j0+4)*9 + hh], bflo(w.z), a0);
          a1 = fmaf(cprob[(j0+5)*9 + hh], bfhi(w.z), a1);
          a0 = fmaf(cprob[(j0+6)*9 + hh], bflo(w.w), a0);
          a1 = fmaf(cprob[(j0+7)*9 + hh], bfhi(w.w), a1);
        }
        psA[half*192 + tm] = a0 + a1;
      }
      __syncthreads();
      if (t < DM) attno[t] = (psA[t] + psA[192+t]) * cainv[t/24];
      __syncthreads();
      // --- CA out + residual + LN ---
      skgemv4(WL + OFF4_CAO, attno, caoutb + l*DM);
      __syncthreads();
      ln_ps4(lng + (l*3+1)*DM, lnb + (l*3+1)*DM);
      // --- FF1: 512 cols split-K2 = 1024 units ---
      {
        int ks = t >> 9, o = t & 511;
        psA[t] = (ks ? 0.f : ff1b[l*DFF_+o]) + dotcol<12,512>(WL + OFF4_FF1 + ks*12*512 + o, x + 96*ks);
      }
      __syncthreads();
      if (t < DFF_) hid[t] = gelu_f(psA[t] + psA[512+t]);
      __syncthreads();
      // --- FF2: 192 cols K=512 split-K4 ---
      if (t < 768) {
        int ks = t/192, o = t - ks*192;
        psA[t] = (ks ? 0.f : ff2b[l*DM+o]) + dotcol<16,192>(WL + OFF4_FF2 + ks*16*192 + o, hid + 128*ks);
      }
      __syncthreads();
      ln_ps4(lng + (l*3+2)*DM, lnb + (l*3+2)*DM);
    }
    // --- head: h1(gelu) -> h2 -> feats ; lasts ; adjacency ---
    skgemv4(wp + OFF4_H1, x, h1b);
    __syncthreads();
    if (t < DM) {
      hid[t] = gelu_f((psA[t]+psA[192+t]) + (psA[384+t]+psA[576+t]));
      lasts[i][t] = x[t];
    }
    __syncthreads();
    {
      int ks = t >> 8, o = t & 255;
      psA[t] = (ks ? 0.f : h2b[o]) + dotcol<6,256>(wp + OFF4_H2 + ks*6*256 + o, hid + 48*ks);
    }
    __syncthreads();
    if (t < 256)
      feats[((size_t)b*PP + i)*256 + t] = (psA[t]+psA[256+t]) + (psA[512+t]+psA[768+t]);
    if (t <= i) {
      float a = 0.f;
      for (int d = 0; d < DM; ++d) a = fmaf(lasts[t][d], lasts[i][d], a);
      if (t == 0) {
        adj[((size_t)b*SM + i)*SM + 32] = a;
        adj[((size_t)b*SM + 32)*SM + i] = a;
      } else {
        int j2 = t - 1;
        adj[((size_t)b*SM + j2)*SM + i] = a;
        adj[((size_t)b*SM + i)*SM + j2] = a;
      }
    }
    __syncthreads();
  }
}

// ---------------- launch ----------------
extern "C" void kernel_launch(void* const* d_in, const int* in_sizes, int n_in,
                              void* d_out, int out_size, void* d_ws, size_t ws_size,
                              hipStream_t stream) {
  (void)in_sizes; (void)n_in; (void)out_size; (void)ws_size;
  const float* x_in    = (const float*)d_in[0];
  const int*   ei      = (const int*)d_in[1];
  const int*   tgt_idx = (const int*)d_in[2];
  const float* gat1_w  = (const float*)d_in[5];
  const float* g1as    = (const float*)d_in[6];
  const float* g1ad    = (const float*)d_in[7];
  const float* g1b     = (const float*)d_in[8];
  const float* gat2_w  = (const float*)d_in[9];
  const float* g2as    = (const float*)d_in[10];
  const float* g2ad    = (const float*)d_in[11];
  const float* g2b     = (const float*)d_in[12];
  const float* saqkvw  = (const float*)d_in[13];
  const float* saqkvb  = (const float*)d_in[14];
  const float* saoutw  = (const float*)d_in[15];
  const float* saoutb  = (const float*)d_in[16];
  const float* caqkvw  = (const float*)d_in[17];
  const float* caqkvb  = (const float*)d_in[18];
  const float* caoutw  = (const float*)d_in[19];
  const float* caoutb  = (const float*)d_in[20];
  const float* ff1w    = (const float*)d_in[21];
  const float* ff1b    = (const float*)d_in[22];
  const float* ff2w    = (const float*)d_in[23];
  const float* ff2b    = (const float*)d_in[24];
  const float* lng     = (const float*)d_in[25];
  const float* lnb     = (const float*)d_in[26];
  const float* h1w     = (const float*)d_in[27];
  const float* h1b     = (const float*)d_in[28];
  const float* h2w     = (const float*)d_in[29];
  const float* h2b     = (const float*)d_in[30];

  float* ws  = (float*)d_ws;
  float* out = (float*)d_out;
  float* adj = out + (size_t)BZ*PP*256;

  const int* src = ei;
  const int* dst = ei + NEDGE;

  int* cnt  = (int*)(ws + O_CNT);
  int* base = (int*)(ws + O_BASE);
  int* fill = (int*)(ws + O_FILL);
  int* csrc = (int*)(ws + O_CSRC);

  hipLaunchKernelGGL(zero_kernel, dim3(545), dim3(256), 0, stream, adj, cnt, fill);

  // ---- GAT1 ----
  hipLaunchKernelGGL((gemm_nt<0,false>), dim3(C1/64, NNODES/64), dim3(256), 0, stream,
                     x_in, gat1_w, (const float*)nullptr, ws + O_XP1, (__hip_bfloat16*)nullptr,
                     NNODES, C1, FIN);
  hipLaunchKernelGGL((al_kernel<4,96>), dim3(NNODES*4/256), dim3(256), 0, stream,
                     ws+O_XP1, g1as, g1ad, ws+O_AL1S, ws+O_AL1D);
  hipLaunchKernelGGL(count_kernel, dim3(NEDGE/256), dim3(256), 0, stream, dst, cnt);
  hipLaunchKernelGGL(scan_kernel, dim3(1), dim3(1024), 0, stream, cnt, base);
  hipLaunchKernelGGL(scatter_kernel, dim3(NEL/256), dim3(256), 0, stream, src, dst, base, fill, csrc);
  hipLaunchKernelGGL((agg_kernel<4,96,true>), dim3(NNODES), dim3(128), 0, stream,
                     ws+O_XP1, ws+O_AL1S, ws+O_AL1D, cnt, base, csrc, g1b, ws+O_H);

  // ---- GAT2 ----
  hipLaunchKernelGGL((gemm_nt<0,false>), dim3(DM/64, NNODES/64), dim3(256), 0, stream,
                     ws+O_H, gat2_w, (const float*)nullptr, ws+O_XP2, (__hip_bfloat16*)nullptr,
                     NNODES, DM, C1);
  hipLaunchKernelGGL((al_kernel<1,192>), dim3(NNODES/256), dim3(256), 0, stream,
                     ws+O_XP2, g2as, g2ad, ws+O_AL2S, ws+O_AL2D);
  hipLaunchKernelGGL((agg_kernel<1,192,false>), dim3(NNODES), dim3(128), 0, stream,
                     ws+O_XP2, ws+O_AL2S, ws+O_AL2D, cnt, base, csrc, g2b, ws+O_MEM);

  // ---- pack decode weights to bf16 [K/8][N] uint4 ----
  uint4* wp = (uint4*)(ws + O_WP);
  auto PK = [&](const float* Wsrc, int off_u4, int N, int K) {
    hipLaunchKernelGGL(pack_kernel, dim3((N*(K/8)+255)/256), dim3(256), 0, stream,
                       Wsrc, wp + off_u4, N, K);
  };
  for (int l = 0; l < LL; ++l) {
    PK(saqkvw + (size_t)l*110592, l*PL4 + OFF4_QKV, 576, 192);
    PK(saoutw + (size_t)l*36864,  l*PL4 + OFF4_SAO, 192, 192);
    PK(caqkvw + (size_t)l*110592, l*PL4 + OFF4_CAQ, 192, 192);  // first 192 rows = Wq
    PK(caoutw + (size_t)l*36864,  l*PL4 + OFF4_CAO, 192, 192);
    PK(ff1w   + (size_t)l*98304,  l*PL4 + OFF4_FF1, 512, 192);
    PK(ff2w   + (size_t)l*98304,  l*PL4 + OFF4_FF2, 192, 512);
  }
  PK(h1w, OFF4_H1, 192, 192);
  PK(h2w, OFF4_H2, 256, 192);

  hipLaunchKernelGGL(pe_kernel, dim3((SM*DM+255)/256), dim3(256), 0, stream, ws+O_PE);

  // ---- CA K (normal layout) and V (transposed [dim][node]) hoisted per layer ----
  __hip_bfloat16* kvk = (__hip_bfloat16*)(ws + O_KVK);
  __hip_bfloat16* vT  = (__hip_bfloat16*)(ws + O_VT);
  for (int l = 0; l < LL; ++l) {
    // K[l] = mem @ Wk^T + bk   -> [node][192]
    hipLaunchKernelGGL((gemm_nt<1,true>), dim3(DM/64, NNODES/64), dim3(256), 0, stream,
                       ws+O_MEM, caqkvw + (size_t)l*110592 + (size_t)192*192,
                       caqkvb + l*576 + 192, (float*)nullptr,
                       kvk + (size_t)l*NNODES*DM, NNODES, DM, DM);
    // V^T[l] = Wv @ mem^T + bv (row bias) -> [dim][node]
    hipLaunchKernelGGL((gemm_nt<2,true>), dim3(NNODES/64, DM/64), dim3(256), 0, stream,
                       caqkvw + (size_t)l*110592 + (size_t)2*192*192, ws+O_MEM,
                       caqkvb + l*576 + 384, (float*)nullptr,
                       vT + (size_t)l*DM*NNODES, DM, NNODES, DM);
  }

  hipLaunchKernelGGL(decode_kernel, dim3(BZ), dim3(1024), 0, stream,
                     ws+O_MEM, (const u16*)kvk, (const u16*)vT, wp, ws+O_PE,
                     (u16*)(ws+O_VSAT), tgt_idx,
                     saqkvb, saoutb, caqkvb, caoutb, ff1b, ff2b, lng, lnb, h1b, h2b,
                     out, adj);
}